// Round 9
// baseline (442.163 us; speedup 1.0000x reference)
//
#include <hip/hip_runtime.h>

#define NS 128
#define NP 32
#define HD 32
#define ED 16
#define GH 72
#define GO 8
#define MD 64
#define TT 8
#define NB (NS*NP)

#define SLOT 272   // floats per slot: 256 data + 4 per-wave flags + pad
#define WS_NEED (256*SLOT*4)

typedef float v2f __attribute__((ext_vector_type(2)));

__device__ __forceinline__ float sigm(float x){ return 1.0f/(1.0f+__expf(-x)); }
__device__ __forceinline__ float tanhfast(float x){ return 1.0f - 2.0f/(__expf(2.0f*x)+1.0f); }
__device__ __forceinline__ unsigned rne16(float f){
  unsigned u = __float_as_uint(f);
  u += 0x7fffu + ((u>>16)&1u);
  return u>>16;
}
__device__ __forceinline__ float lo16(unsigned v){ return __uint_as_float(v<<16); }
__device__ __forceinline__ float hi16(unsigned v){ return __uint_as_float(v & 0xffff0000u); }

// ==================== split kernel: 256 blocks, (scene, m) per block ====================
__global__ __launch_bounds__(1024, 1) void decoder_kernel_split(
    const float* __restrict__ last_pos, const float* __restrict__ last_pos_rel,
    const float* __restrict__ hh, const float* __restrict__ ch,
    const int*  __restrict__ eg,
    const float* __restrict__ W_se, const float* __restrict__ b_se,
    const float* __restrict__ Wih, const float* __restrict__ Whh,
    const float* __restrict__ bih, const float* __restrict__ bhh,
    const float* __restrict__ W_hp, const float* __restrict__ b_hp,
    const float* __restrict__ W_pse, const float* __restrict__ b_pse,
    const float* __restrict__ W1a, const float* __restrict__ W2a,
    const float* __restrict__ W1b, const float* __restrict__ W2b,
    const float* __restrict__ W_m1, const float* __restrict__ b_m1,
    const float* __restrict__ W_m2, const float* __restrict__ b_m2,
    float* __restrict__ out, float* __restrict__ ws)
{
  const int tid   = threadIdx.x;
  const int scn   = blockIdx.x >> 1;
  const int myM   = blockIdx.x & 1;
  const int lane  = tid & 31;
  const int grp32 = tid >> 5;      // 0..31

  // uni overlays: G[32][128] gate staging (16 KB) <-> a1[32][76] (9.7 KB)
  __shared__ __align__(16) float uni[4096];
  __shared__ __align__(16) unsigned W1p[16][GH];   // own m, bf16 pairs (hk, hk+1)
  __shared__ __align__(16) float W2l[GH][GO];      // own m
  __shared__ __align__(16) float Wp1[2][GH];       // own m
  __shared__ __align__(16) float c1l[GH];          // own m
  __shared__ __align__(16) float hbuf[NP][HD];
  __shared__ __align__(16) float h2buf[NP][36];
  __shared__ __align__(16) float GS[5][GH];        // own m
  __shared__ __align__(16) float phbuf[NP][16];
  __shared__ __align__(16) unsigned Wm1p[48][32];
  __shared__ __align__(16) unsigned Wm2p[32][32];
  __shared__ float lpbuf[NP][2], rpbuf[NP][2], Whp[HD][2];
  __shared__ float bm1l[MD], bm2l[HD], bhp2[2];
  __shared__ unsigned bm[NP];
  __shared__ float invn[NP];
  __shared__ int gl[NP];

  float* const a1 = uni;   // [32][76]

  const int myslot = (scn*2 + myM)*SLOT;
  const int pslot  = (scn*2 + 1 - myM)*SLOT;

  // ---------- persistent per-thread LSTM row weights (global read ONCE) ----------
  const int myrow = tid & 127;
  const int pq4   = tid >> 7;
  float wrow[HD];
  #pragma unroll
  for (int c = 0; c < HD/4; c++) {
    float4 w = *(const float4*)(Whh + myrow*HD + c*4);
    wrow[c*4+0]=w.x; wrow[c*4+1]=w.y; wrow[c*4+2]=w.z; wrow[c*4+3]=w.w;
  }
  float wf0 = 0.f, wf1 = 0.f, bfr = bih[myrow] + bhh[myrow];
  #pragma unroll
  for (int e = 0; e < ED; e++) {
    float wv = Wih[myrow*ED + e];
    wf0 = fmaf(W_se[e],    wv, wf0);
    wf1 = fmaf(W_se[ED+e], wv, wf1);
    bfr = fmaf(b_se[e],    wv, bfr);
  }

  float creg = ch[(scn*NP + grp32)*HD + lane];
  hbuf[grp32][lane] = hh[(scn*NP + grp32)*HD + lane];

  // ---------- setup ----------
  if (tid < NP) {
    int gi = eg[scn*NP + tid];
    gl[tid] = gi;
    unsigned sm = 0;
    for (int j = 0; j < NP; j++) {
      int gj = eg[scn*NP + j];
      bool sj = (j == tid) || (gi == gj && gi != 0);
      sm |= ((unsigned)sj) << j;
    }
    unsigned mk = myM ? ((~sm) | (1u << tid)) : sm;
    bm[tid] = mk;
    invn[tid] = 1.0f/(float)__popc(mk);
  }
  if (tid < 64) {
    int p = tid >> 1, k = tid & 1;
    lpbuf[p][k] = last_pos[(scn*NP+p)*2+k];
    rpbuf[p][k] = last_pos_rel[(scn*NP+p)*2+k];
    Whp[p][k]   = W_hp[tid];
    bm1l[tid]   = b_m1[tid];
  }
  if (tid < 32) bm2l[tid] = b_m2[tid];
  if (tid < 2)  bhp2[tid] = b_hp[tid];
  const float* W1my = myM ? W1b : W1a;
  if (tid < GH) {   // folded Wp1 = W_pse@W1[:16], c1 = b_pse@W1[:16] (own m)
    int d = tid;
    float s0 = 0.f, s1 = 0.f, sc1 = 0.f;
    for (int e = 0; e < ED; e++) {
      float w = W1my[e*GH + d];
      s0  += W_pse[e]    * w;
      s1  += W_pse[ED+e] * w;
      sc1 += b_pse[e]    * w;
    }
    Wp1[0][d] = s0; Wp1[1][d] = s1; c1l[d] = sc1;
  }
  if (tid < GH*GO) {   // W2 own m, fp32 (576)
    W2l[tid/GO][tid%GO] = (myM ? W2b : W2a)[tid];
  }
  #pragma unroll
  for (int r = 0; r < 2; r++) {  // W1p own m, packed bf16 (1152: two passes)
    int u = tid + 1024*r;
    if (u < 16*GH) {
      int k2 = u/GH, d = u%GH;
      unsigned lo = rne16(W1my[(ED+2*k2  )*GH + d]);
      unsigned hi = rne16(W1my[(ED+2*k2+1)*GH + d]);
      W1p[k2][d] = lo | (hi << 16);
    }
  }
  #pragma unroll
  for (int r = 0; r < 2; r++) {   // Wm1p packed bf16 (1536)
    int u = tid + 1024*r;
    if (u < 1536) {
      int k = u >> 5, uu = u & 31;
      Wm1p[k][uu] = rne16(W_m1[k*MD + uu]) | (rne16(W_m1[k*MD + 32 + uu]) << 16);
    }
  }
  {  // Wm2p packed bf16 (1024)
    int k = tid >> 5, uu = tid & 31;
    Wm2p[k][uu] = rne16(W_m2[k*HD + uu]) | (rne16(W_m2[(k+32)*HD + uu]) << 16);
  }
  __syncthreads();

  // ---------------- time steps ----------------
  for (int t = 0; t < TT; t++) {
    // P1a: gates[p][myrow] for 4 peds (redundant in both blocks; deterministic)
    {
      float rG[4];
      #pragma unroll
      for (int pp2 = 0; pp2 < 4; pp2++) {
        int p = pq4*4 + pp2;
        float acc = fmaf(rpbuf[p][0], wf0, fmaf(rpbuf[p][1], wf1, bfr));
        #pragma unroll
        for (int c = 0; c < 8; c++) {
          float4 h4 = *(const float4*)&hbuf[p][c*4];
          acc = fmaf(h4.x, wrow[c*4+0], acc);
          acc = fmaf(h4.y, wrow[c*4+1], acc);
          acc = fmaf(h4.z, wrow[c*4+2], acc);
          acc = fmaf(h4.w, wrow[c*4+3], acc);
        }
        rG[pp2] = acc;
      }
      #pragma unroll
      for (int pp2 = 0; pp2 < 4; pp2++) uni[(pq4*4+pp2)*128 + myrow] = rG[pp2];
    }
    __syncthreads();

    // P1b: activations, c/h2 update; rel_pos reduction; out store (m=0 block only)
    {
      int p = grp32, n = lane;
      float gi_ = uni[p*128 +       n];
      float gf_ = uni[p*128 +  32 + n];
      float gg_ = uni[p*128 +  64 + n];
      float go_ = uni[p*128 +  96 + n];
      float c2 = sigm(gf_)*creg + sigm(gi_)*tanhfast(gg_);
      creg = c2;
      float h2 = sigm(go_)*tanhfast(c2);
      h2buf[p][n] = h2;
      float r0 = h2 * Whp[n][0];
      float r1 = h2 * Whp[n][1];
      #pragma unroll
      for (int off = 1; off < 32; off <<= 1) {
        r0 += __shfl_xor(r0, off, 32);
        r1 += __shfl_xor(r1, off, 32);
      }
      r0 += bhp2[0]; r1 += bhp2[1];
      if (n == 0) {
        if (myM == 0) {
          out[t*NB*2 + (scn*NP+p)*2 + 0] = r0;
          out[t*NB*2 + (scn*NP+p)*2 + 1] = r1;
        }
        rpbuf[p][0] = r0;  rpbuf[p][1] = r1;
        lpbuf[p][0] += r0; lpbuf[p][1] += r1;
      }
    }
    __syncthreads();

    // P2: a1[j][d] + GS group sums (own m). j = lane invariant across passes.
    {
      const int j = lane;
      float lpj0 = lpbuf[j][0], lpj1 = lpbuf[j][1];
      float h2row[HD];
      #pragma unroll
      for (int c = 0; c < 8; c++) {
        float4 v = *(const float4*)&h2buf[j][c*4];
        h2row[c*4+0]=v.x; h2row[c*4+1]=v.y; h2row[c*4+2]=v.z; h2row[c*4+3]=v.w;
      }
      #pragma unroll
      for (int r = 0; r < 3; r++) {
        int d = grp32 + 32*r;
        if (d < GH) {
          float pp_ = fmaf(lpj0, Wp1[0][d], lpj1*Wp1[1][d]);
          float av = pp_;
          #pragma unroll
          for (int k2 = 0; k2 < 16; k2++) {
            unsigned v = W1p[k2][d];
            av = fmaf(h2row[2*k2  ], lo16(v), av);
            av = fmaf(h2row[2*k2+1], hi16(v), av);
          }
          a1[j*76 + d] = av;
          int gj = gl[j];
          float tot = av;
          float s1 = (gj==1)?av:0.f, s2=(gj==2)?av:0.f, s3=(gj==3)?av:0.f, s4=(gj==4)?av:0.f;
          #pragma unroll
          for (int off = 1; off < 32; off <<= 1) {
            tot += __shfl_xor(tot, off, 32);
            s1  += __shfl_xor(s1,  off, 32);
            s2  += __shfl_xor(s2,  off, 32);
            s3  += __shfl_xor(s3,  off, 32);
            s4  += __shfl_xor(s4,  off, 32);
          }
          if (j < 5) {
            float v2;
            if (myM == 0) v2 = (j==0)?tot:((j==1)?s1:((j==2)?s2:((j==3)?s3:s4)));
            else          v2 = (j==0)?tot:((j==1)?tot-s1:((j==2)?tot-s2:((j==3)?tot-s3:tot-s4)));
            GS[j][d] = v2;
          }
        }
      }
    }
    __syncthreads();

    // P3: pool (own m). One task per thread: i = grp32, j = lane. e recomputed in-register.
    {
      const int j = lane, i = grp32;
      unsigned bmv = bm[i];
      bool mij = (bmv >> j) & 1u;
      bool diag = (j == i);
      int gi = gl[i];
      float in_ = invn[i];
      const float *p0, *p1; float c0, c1c;
      if (diag) {
        if (myM == 0) { p0 = gi ? &GS[gi][0] : (a1 + i*76); c0 = in_; p1 = a1 + i*76; c1c = 0.f; }
        else          { p0 = &GS[gi][0];                    c0 = in_; p1 = a1 + i*76; c1c = gi ? in_ : 0.f; }
      } else if (mij) { p0 = a1 + j*76; c0 = 0.5f; p1 = a1 + i*76; c1c = 0.5f; }
      else            { p0 = a1 + j*76; c0 = 1.0f; p1 = a1 + j*76; c1c = 0.f; }
      float NL0 = -lpbuf[i][0], NL1 = -lpbuf[i][1];
      v2f qv[4];
      #pragma unroll
      for (int h = 0; h < 4; h++) qv[h] = (v2f){0.f, 0.f};
      for (int d4 = 0; d4 < GH/4; d4++) {
        float4 c14 = *(const float4*)&c1l[d4*4];
        float4 w04 = *(const float4*)&Wp1[0][d4*4];
        float4 w14 = *(const float4*)&Wp1[1][d4*4];
        float4 va  = diag ? *(const float4*)(p0 + d4*4)
                          : *(const float4*)(a1 + j*76 + d4*4);
        float4 vb  = *(const float4*)(p1 + d4*4);
        float ex = fmaf(NL1, w14.x, fmaf(NL0, w04.x, c14.x));
        float ey = fmaf(NL1, w14.y, fmaf(NL0, w04.y, c14.y));
        float ez = fmaf(NL1, w14.z, fmaf(NL0, w04.z, c14.z));
        float ew = fmaf(NL1, w14.w, fmaf(NL0, w04.w, c14.w));
        float tv[4];
        tv[0] = fmaxf(fmaf(c0, va.x, fmaf(c1c, vb.x, ex)), 0.f);
        tv[1] = fmaxf(fmaf(c0, va.y, fmaf(c1c, vb.y, ey)), 0.f);
        tv[2] = fmaxf(fmaf(c0, va.z, fmaf(c1c, vb.z, ez)), 0.f);
        tv[3] = fmaxf(fmaf(c0, va.w, fmaf(c1c, vb.w, ew)), 0.f);
        #pragma unroll
        for (int k = 0; k < 4; k++) {
          const v2f* w2p = (const v2f*)&W2l[d4*4+k][0];
          v2f wA = w2p[0], wB = w2p[1], wC = w2p[2], wD = w2p[3];
          v2f tk = {tv[k], tv[k]};
          qv[0] += tk*wA; qv[1] += tk*wB; qv[2] += tk*wC; qv[3] += tk*wD;
        }
      }
      float q[8];
      #pragma unroll
      for (int h = 0; h < 4; h++) { q[2*h] = qv[h][0]; q[2*h+1] = qv[h][1]; }
      float sq[8];
      #pragma unroll
      for (int o = 0; o < 8; o++) sq[o] = mij ? q[o] : 0.f;
      #pragma unroll
      for (int off = 1; off < 32; off <<= 1) {
        #pragma unroll
        for (int o = 0; o < 8; o++) sq[o] += __shfl_xor(sq[o], off, 32);
      }
      float qd[8];
      #pragma unroll
      for (int o = 0; o < 8; o++) qd[o] = __shfl(q[o], i, 32);
      float F[8];
      if (diag) {
        #pragma unroll
        for (int o = 0; o < 8; o++) F[o] = fmaxf(sq[o]*in_, 0.f);
      } else {
        float scl = mij ? 0.5f : 1.0f;
        #pragma unroll
        for (int o = 0; o < 8; o++)
          F[o] = fmaxf((q[o] + (mij ? qd[o] : 0.f))*scl, 0.f);
      }
      #pragma unroll
      for (int off = 1; off < 32; off <<= 1) {
        #pragma unroll
        for (int o = 0; o < 8; o++) F[o] = fmaxf(F[o], __shfl_xor(F[o], off, 32));
      }
      if (j == 0) {
        #pragma unroll
        for (int o = 0; o < 8; o++) phbuf[i][myM*GO + o] = F[o];
      }
    }
    __syncthreads();

    // ---- exchange: per-wave flags, one-way acquire/release (NO RMW anywhere) ----
    {
      const int w = tid >> 6;    // wave id 0..15
      if (w < 4) {
        int pp = tid >> 3, o = tid & 7;
        // data: relaxed agent-scope store (bypasses per-XCD caches appropriately)
        __hip_atomic_store(ws + myslot + tid, phbuf[pp][myM*8 + o],
                           __ATOMIC_RELAXED, __HIP_MEMORY_SCOPE_AGENT);
        // flag: release by lane 0 of this wave (vmcnt drains the wave's data stores)
        if ((tid & 63) == 0)
          __hip_atomic_store((unsigned*)(ws + myslot + 256 + w), (unsigned)(t + 1),
                             __ATOMIC_RELEASE, __HIP_MEMORY_SCOPE_AGENT);
        // acquire-poll partner wave-w flag (read-only; all lanes same address)
        while (__hip_atomic_load((const unsigned*)(ws + pslot + 256 + w),
                                 __ATOMIC_ACQUIRE, __HIP_MEMORY_SCOPE_AGENT)
               != (unsigned)(t + 1))
          __builtin_amdgcn_s_sleep(1);
        float pv = __hip_atomic_load(ws + pslot + tid,
                                     __ATOMIC_RELAXED, __HIP_MEMORY_SCOPE_AGENT);
        phbuf[pp][(1-myM)*8 + o] = pv;
      }
    }
    __syncthreads();

    // P4: mlp (48 -> 64 -> 32, relu both). 32 lanes per ped (redundant in both blocks).
    {
      int p = grp32, u = lane;
      float in48[48];
      #pragma unroll
      for (int c = 0; c < 8; c++) {
        float4 v = *(const float4*)&h2buf[p][c*4];
        in48[c*4+0]=v.x; in48[c*4+1]=v.y; in48[c*4+2]=v.z; in48[c*4+3]=v.w;
      }
      #pragma unroll
      for (int c = 0; c < 4; c++) {
        float4 v = *(const float4*)&phbuf[p][c*4];
        in48[32+c*4+0]=v.x; in48[32+c*4+1]=v.y; in48[32+c*4+2]=v.z; in48[32+c*4+3]=v.w;
      }
      float m1lo = bm1l[u], m1hi = bm1l[32 + u];
      #pragma unroll
      for (int k = 0; k < 48; k++) {
        unsigned v = Wm1p[k][u];
        m1lo = fmaf(in48[k], lo16(v), m1lo);
        m1hi = fmaf(in48[k], hi16(v), m1hi);
      }
      m1lo = fmaxf(m1lo, 0.f); m1hi = fmaxf(m1hi, 0.f);
      float acc = bm2l[u];
      #pragma unroll
      for (int k = 0; k < 32; k++) {
        unsigned v = Wm2p[k][u];
        acc = fmaf(__shfl(m1lo, k, 32), lo16(v), acc);
        acc = fmaf(__shfl(m1hi, k, 32), hi16(v), acc);
      }
      hbuf[p][u] = fmaxf(acc, 0.f);
    }
    __syncthreads();
  }
}

// ==================== mono fallback: 128 blocks (R4/R6 kernel, verified) ====================
__global__ __launch_bounds__(1024, 1) void decoder_kernel_mono(
    const float* __restrict__ last_pos, const float* __restrict__ last_pos_rel,
    const float* __restrict__ hh, const float* __restrict__ ch,
    const int*  __restrict__ eg,
    const float* __restrict__ W_se, const float* __restrict__ b_se,
    const float* __restrict__ Wih, const float* __restrict__ Whh,
    const float* __restrict__ bih, const float* __restrict__ bhh,
    const float* __restrict__ W_hp, const float* __restrict__ b_hp,
    const float* __restrict__ W_pse, const float* __restrict__ b_pse,
    const float* __restrict__ W1a, const float* __restrict__ W2a,
    const float* __restrict__ W1b, const float* __restrict__ W2b,
    const float* __restrict__ W_m1, const float* __restrict__ b_m1,
    const float* __restrict__ W_m2, const float* __restrict__ b_m2,
    float* __restrict__ out)
{
  const int tid   = threadIdx.x;
  const int scn   = blockIdx.x;
  const int lane  = tid & 31;
  const int grp32 = tid >> 5;

  __shared__ __align__(16) float uni[4864];
  __shared__ __align__(16) unsigned W1p[2][16][GH];
  __shared__ __align__(16) float W2l[2][GH][GO];
  __shared__ __align__(16) float Wp1[2][2][GH];
  __shared__ __align__(16) float c1l[2][GH];
  __shared__ __align__(16) float hbuf[NP][HD];
  __shared__ __align__(16) float h2buf[NP][36];
  __shared__ __align__(16) float GS[2][5][GH];
  __shared__ __align__(16) float phbuf[NP][16];
  __shared__ __align__(16) unsigned Wm1p[48][32];
  __shared__ __align__(16) unsigned Wm2p[32][32];
  __shared__ float lpbuf[NP][2], rpbuf[NP][2], Whp[HD][2];
  __shared__ float bm1l[MD], bm2l[HD], bhp2[2];
  __shared__ unsigned bm[2][NP];
  __shared__ float invn[2][NP];
  __shared__ int gl[NP];

  const int myrow = tid & 127;
  const int pq4   = tid >> 7;
  float wrow[HD];
  #pragma unroll
  for (int c = 0; c < HD/4; c++) {
    float4 w = *(const float4*)(Whh + myrow*HD + c*4);
    wrow[c*4+0]=w.x; wrow[c*4+1]=w.y; wrow[c*4+2]=w.z; wrow[c*4+3]=w.w;
  }
  float wf0 = 0.f, wf1 = 0.f, bfr = bih[myrow] + bhh[myrow];
  #pragma unroll
  for (int e = 0; e < ED; e++) {
    float wv = Wih[myrow*ED + e];
    wf0 = fmaf(W_se[e],    wv, wf0);
    wf1 = fmaf(W_se[ED+e], wv, wf1);
    bfr = fmaf(b_se[e],    wv, bfr);
  }
  float creg = ch[(scn*NP + grp32)*HD + lane];
  hbuf[grp32][lane] = hh[(scn*NP + grp32)*HD + lane];

  if (tid < NP) {
    int gi = eg[scn*NP + tid];
    gl[tid] = gi;
    unsigned sm = 0;
    for (int j = 0; j < NP; j++) {
      int gj = eg[scn*NP + j];
      bool sj = (j == tid) || (gi == gj && gi != 0);
      sm |= ((unsigned)sj) << j;
    }
    unsigned dm = (~sm) | (1u << tid);
    bm[0][tid] = sm; bm[1][tid] = dm;
    invn[0][tid] = 1.0f/(float)__popc(sm);
    invn[1][tid] = 1.0f/(float)__popc(dm);
  }
  if (tid < 64) {
    int p = tid >> 1, k = tid & 1;
    lpbuf[p][k] = last_pos[(scn*NP+p)*2+k];
    rpbuf[p][k] = last_pos_rel[(scn*NP+p)*2+k];
    Whp[p][k]   = W_hp[tid];
    bm1l[tid]   = b_m1[tid];
  }
  if (tid < 32) bm2l[tid] = b_m2[tid];
  if (tid < 2)  bhp2[tid] = b_hp[tid];
  if (tid < 2*GH) {
    int m = tid / GH, d = tid % GH;
    const float* W1 = m ? W1b : W1a;
    float s0 = 0.f, s1 = 0.f, sc1 = 0.f;
    for (int e = 0; e < ED; e++) {
      float w = W1[e*GH + d];
      s0 += W_pse[e]*w; s1 += W_pse[ED+e]*w; sc1 += b_pse[e]*w;
    }
    Wp1[m][0][d] = s0; Wp1[m][1][d] = s1; c1l[m][d] = sc1;
  }
  {
    int u = tid;
    if (u < 2*GH*GO) {
      int m = u/(GH*GO), rest = u%(GH*GO);
      W2l[m][rest/GO][rest%GO] = (m ? W2b : W2a)[rest];
    }
    if (tid < 128) {
      int u2 = tid + 1024;
      int m = u2/(GH*GO), rest = u2%(GH*GO);
      W2l[m][rest/GO][rest%GO] = (m ? W2b : W2a)[rest];
    }
  }
  #pragma unroll
  for (int r = 0; r < 3; r++) {
    int u = tid + 1024*r;
    if (u < 2304) {
      int m = u/1152, rest = u%1152, k2 = rest/GH, d = rest%GH;
      const float* W1 = m ? W1b : W1a;
      W1p[m][k2][d] = rne16(W1[(ED+2*k2)*GH + d]) | (rne16(W1[(ED+2*k2+1)*GH + d]) << 16);
    }
  }
  #pragma unroll
  for (int r = 0; r < 2; r++) {
    int u = tid + 1024*r;
    if (u < 1536) {
      int k = u >> 5, uu = u & 31;
      Wm1p[k][uu] = rne16(W_m1[k*MD + uu]) | (rne16(W_m1[k*MD + 32 + uu]) << 16);
    }
  }
  {
    int k = tid >> 5, uu = tid & 31;
    Wm2p[k][uu] = rne16(W_m2[k*HD + uu]) | (rne16(W_m2[(k+32)*HD + uu]) << 16);
  }
  __syncthreads();

  for (int t = 0; t < TT; t++) {
    {
      float rG[4];
      #pragma unroll
      for (int pp2 = 0; pp2 < 4; pp2++) {
        int p = pq4*4 + pp2;
        float acc = fmaf(rpbuf[p][0], wf0, fmaf(rpbuf[p][1], wf1, bfr));
        #pragma unroll
        for (int c = 0; c < 8; c++) {
          float4 h4 = *(const float4*)&hbuf[p][c*4];
          acc = fmaf(h4.x, wrow[c*4+0], acc);
          acc = fmaf(h4.y, wrow[c*4+1], acc);
          acc = fmaf(h4.z, wrow[c*4+2], acc);
          acc = fmaf(h4.w, wrow[c*4+3], acc);
        }
        rG[pp2] = acc;
      }
      #pragma unroll
      for (int pp2 = 0; pp2 < 4; pp2++) uni[(pq4*4+pp2)*128 + myrow] = rG[pp2];
    }
    __syncthreads();
    {
      int p = grp32, n = lane;
      float gi_ = uni[p*128 + n];
      float gf_ = uni[p*128 + 32 + n];
      float gg_ = uni[p*128 + 64 + n];
      float go_ = uni[p*128 + 96 + n];
      float c2 = sigm(gf_)*creg + sigm(gi_)*tanhfast(gg_);
      creg = c2;
      float h2 = sigm(go_)*tanhfast(c2);
      h2buf[p][n] = h2;
      float r0 = h2 * Whp[n][0];
      float r1 = h2 * Whp[n][1];
      #pragma unroll
      for (int off = 1; off < 32; off <<= 1) {
        r0 += __shfl_xor(r0, off, 32);
        r1 += __shfl_xor(r1, off, 32);
      }
      r0 += bhp2[0]; r1 += bhp2[1];
      if (n == 0) {
        out[t*NB*2 + (scn*NP+p)*2 + 0] = r0;
        out[t*NB*2 + (scn*NP+p)*2 + 1] = r1;
        rpbuf[p][0] = r0;  rpbuf[p][1] = r1;
        lpbuf[p][0] += r0; lpbuf[p][1] += r1;
      }
    }
    __syncthreads();
    {
      const int j = lane;
      float lpj0 = lpbuf[j][0], lpj1 = lpbuf[j][1];
      float h2row[HD];
      #pragma unroll
      for (int c = 0; c < 8; c++) {
        float4 v = *(const float4*)&h2buf[j][c*4];
        h2row[c*4+0]=v.x; h2row[c*4+1]=v.y; h2row[c*4+2]=v.z; h2row[c*4+3]=v.w;
      }
      #pragma unroll
      for (int r = 0; r < 5; r++) {
        int rest = grp32 + 32*r;
        if (rest < 144) {
          int m = rest >= 72 ? 1 : 0;
          int d = rest - 72*m;
          float pp_ = fmaf(lpj0, Wp1[m][0][d], lpj1*Wp1[m][1][d]);
          float av = pp_;
          #pragma unroll
          for (int k2 = 0; k2 < 16; k2++) {
            unsigned v = W1p[m][k2][d];
            av = fmaf(h2row[2*k2], lo16(v), av);
            av = fmaf(h2row[2*k2+1], hi16(v), av);
          }
          uni[m*2432 + j*76 + d] = av;
          int gj = gl[j];
          float tot = av;
          float s1 = (gj==1)?av:0.f, s2=(gj==2)?av:0.f, s3=(gj==3)?av:0.f, s4=(gj==4)?av:0.f;
          #pragma unroll
          for (int off = 1; off < 32; off <<= 1) {
            tot += __shfl_xor(tot, off, 32);
            s1 += __shfl_xor(s1, off, 32);
            s2 += __shfl_xor(s2, off, 32);
            s3 += __shfl_xor(s3, off, 32);
            s4 += __shfl_xor(s4, off, 32);
          }
          if (j < 5) {
            float v2;
            if (m == 0) v2 = (j==0)?tot:((j==1)?s1:((j==2)?s2:((j==3)?s3:s4)));
            else        v2 = (j==0)?tot:((j==1)?tot-s1:((j==2)?tot-s2:((j==3)?tot-s3:tot-s4)));
            GS[m][j][d] = v2;
          }
        }
      }
    }
    __syncthreads();
    {
      const int j   = lane;
      const int m   = tid >> 9;
      const int sub = (tid >> 5) & 15;
      const float* am = uni + m*2432;
      int   I2[2] = {sub, sub + 16};
      const float *P0[2], *P1[2];
      float C0[2], C1[2], NL0[2], NL1[2];
      bool  MIJ[2], DIAG[2];
      v2f qv[2][4];
      #pragma unroll
      for (int r = 0; r < 2; r++) {
        int i = I2[r];
        unsigned bmv = bm[m][i];
        bool mij = (bmv >> j) & 1u;
        bool diag = (j == i);
        int gi = gl[i];
        float in_ = invn[m][i];
        const float *p0, *p1; float c0, c1c;
        if (diag) {
          if (m == 0) { p0 = gi ? &GS[0][gi][0] : (am + i*76); c0 = in_; p1 = am + i*76; c1c = 0.f; }
          else        { p0 = &GS[1][gi][0];                    c0 = in_; p1 = am + i*76; c1c = gi ? in_ : 0.f; }
        } else if (mij) { p0 = am + j*76; c0 = 0.5f; p1 = am + i*76; c1c = 0.5f; }
        else            { p0 = am + j*76; c0 = 1.0f; p1 = am + j*76; c1c = 0.f; }
        P0[r]=p0; P1[r]=p1; C0[r]=c0; C1[r]=c1c; MIJ[r]=mij; DIAG[r]=diag;
        NL0[r] = -lpbuf[i][0]; NL1[r] = -lpbuf[i][1];
        #pragma unroll
        for (int h = 0; h < 4; h++) qv[r][h] = (v2f){0.f, 0.f};
      }
      for (int d4 = 0; d4 < GH/4; d4++) {
        float4 c14 = *(const float4*)&c1l[m][d4*4];
        float4 w04 = *(const float4*)&Wp1[m][0][d4*4];
        float4 w14 = *(const float4*)&Wp1[m][1][d4*4];
        float4 vaS = *(const float4*)(am + j*76 + d4*4);
        float4 va0 = vaS, va1 = vaS;
        if (DIAG[0]) va0 = *(const float4*)(P0[0] + d4*4);
        if (DIAG[1]) va1 = *(const float4*)(P0[1] + d4*4);
        float4 vb0 = *(const float4*)(P1[0] + d4*4);
        float4 vb1 = *(const float4*)(P1[1] + d4*4);
        float e0x = fmaf(NL1[0], w14.x, fmaf(NL0[0], w04.x, c14.x));
        float e0y = fmaf(NL1[0], w14.y, fmaf(NL0[0], w04.y, c14.y));
        float e0z = fmaf(NL1[0], w14.z, fmaf(NL0[0], w04.z, c14.z));
        float e0w = fmaf(NL1[0], w14.w, fmaf(NL0[0], w04.w, c14.w));
        float e1x = fmaf(NL1[1], w14.x, fmaf(NL0[1], w04.x, c14.x));
        float e1y = fmaf(NL1[1], w14.y, fmaf(NL0[1], w04.y, c14.y));
        float e1z = fmaf(NL1[1], w14.z, fmaf(NL0[1], w04.z, c14.z));
        float e1w = fmaf(NL1[1], w14.w, fmaf(NL0[1], w04.w, c14.w));
        float tv0[4], tv1[4];
        tv0[0] = fmaxf(fmaf(C0[0], va0.x, fmaf(C1[0], vb0.x, e0x)), 0.f);
        tv0[1] = fmaxf(fmaf(C0[0], va0.y, fmaf(C1[0], vb0.y, e0y)), 0.f);
        tv0[2] = fmaxf(fmaf(C0[0], va0.z, fmaf(C1[0], vb0.z, e0z)), 0.f);
        tv0[3] = fmaxf(fmaf(C0[0], va0.w, fmaf(C1[0], vb0.w, e0w)), 0.f);
        tv1[0] = fmaxf(fmaf(C0[1], va1.x, fmaf(C1[1], vb1.x, e1x)), 0.f);
        tv1[1] = fmaxf(fmaf(C0[1], va1.y, fmaf(C1[1], vb1.y, e1y)), 0.f);
        tv1[2] = fmaxf(fmaf(C0[1], va1.z, fmaf(C1[1], vb1.z, e1z)), 0.f);
        tv1[3] = fmaxf(fmaf(C0[1], va1.w, fmaf(C1[1], vb1.w, e1w)), 0.f);
        #pragma unroll
        for (int k = 0; k < 4; k++) {
          const v2f* w2p = (const v2f*)&W2l[m][d4*4+k][0];
          v2f wA = w2p[0], wB = w2p[1], wC = w2p[2], wD = w2p[3];
          v2f t0 = {tv0[k], tv0[k]};
          qv[0][0] += t0*wA; qv[0][1] += t0*wB; qv[0][2] += t0*wC; qv[0][3] += t0*wD;
          v2f t1 = {tv1[k], tv1[k]};
          qv[1][0] += t1*wA; qv[1][1] += t1*wB; qv[1][2] += t1*wC; qv[1][3] += t1*wD;
        }
      }
      #pragma unroll
      for (int r = 0; r < 2; r++) {
        float q[8];
        #pragma unroll
        for (int h = 0; h < 4; h++) { q[2*h] = qv[r][h][0]; q[2*h+1] = qv[r][h][1]; }
        float sq[8];
        #pragma unroll
        for (int o = 0; o < 8; o++) sq[o] = MIJ[r] ? q[o] : 0.f;
        #pragma unroll
        for (int off = 1; off < 32; off <<= 1) {
          #pragma unroll
          for (int o = 0; o < 8; o++) sq[o] += __shfl_xor(sq[o], off, 32);
        }
        float qd[8];
        #pragma unroll
        for (int o = 0; o < 8; o++) qd[o] = __shfl(q[o], I2[r], 32);
        float in_ = invn[m][I2[r]];
        float F[8];
        if (DIAG[r]) {
          #pragma unroll
          for (int o = 0; o < 8; o++) F[o] = fmaxf(sq[o]*in_, 0.f);
        } else {
          float scl = MIJ[r] ? 0.5f : 1.0f;
          #pragma unroll
          for (int o = 0; o < 8; o++)
            F[o] = fmaxf((q[o] + (MIJ[r] ? qd[o] : 0.f))*scl, 0.f);
        }
        #pragma unroll
        for (int off = 1; off < 32; off <<= 1) {
          #pragma unroll
          for (int o = 0; o < 8; o++) F[o] = fmaxf(F[o], __shfl_xor(F[o], off, 32));
        }
        if (j == 0) {
          #pragma unroll
          for (int o = 0; o < 8; o++) phbuf[I2[r]][m*GO + o] = F[o];
        }
      }
    }
    __syncthreads();
    {
      int p = grp32, u = lane;
      float in48[48];
      #pragma unroll
      for (int c = 0; c < 8; c++) {
        float4 v = *(const float4*)&h2buf[p][c*4];
        in48[c*4+0]=v.x; in48[c*4+1]=v.y; in48[c*4+2]=v.z; in48[c*4+3]=v.w;
      }
      #pragma unroll
      for (int c = 0; c < 4; c++) {
        float4 v = *(const float4*)&phbuf[p][c*4];
        in48[32+c*4+0]=v.x; in48[32+c*4+1]=v.y; in48[32+c*4+2]=v.z; in48[32+c*4+3]=v.w;
      }
      float m1lo = bm1l[u], m1hi = bm1l[32 + u];
      #pragma unroll
      for (int k = 0; k < 48; k++) {
        unsigned v = Wm1p[k][u];
        m1lo = fmaf(in48[k], lo16(v), m1lo);
        m1hi = fmaf(in48[k], hi16(v), m1hi);
      }
      m1lo = fmaxf(m1lo, 0.f); m1hi = fmaxf(m1hi, 0.f);
      float acc = bm2l[u];
      #pragma unroll
      for (int k = 0; k < 32; k++) {
        unsigned v = Wm2p[k][u];
        acc = fmaf(__shfl(m1lo, k, 32), lo16(v), acc);
        acc = fmaf(__shfl(m1hi, k, 32), hi16(v), acc);
      }
      hbuf[p][u] = fmaxf(acc, 0.f);
    }
    __syncthreads();
  }
}

extern "C" void kernel_launch(void* const* d_in, const int* in_sizes, int n_in,
                              void* d_out, int out_size, void* d_ws, size_t ws_size,
                              hipStream_t stream) {
  (void)in_sizes; (void)n_in; (void)out_size;
  const float* last_pos     = (const float*)d_in[0];
  const float* last_pos_rel = (const float*)d_in[1];
  const float* hh           = (const float*)d_in[2];
  const float* ch           = (const float*)d_in[3];
  const int*  eg            = (const int*) d_in[5];
  const float* W_se  = (const float*)d_in[6];
  const float* b_se  = (const float*)d_in[7];
  const float* Wih   = (const float*)d_in[8];
  const float* Whh   = (const float*)d_in[9];
  const float* bih   = (const float*)d_in[10];
  const float* bhh   = (const float*)d_in[11];
  const float* W_hp  = (const float*)d_in[12];
  const float* b_hp  = (const float*)d_in[13];
  const float* W_pse = (const float*)d_in[14];
  const float* b_pse = (const float*)d_in[15];
  const float* W1a   = (const float*)d_in[16];
  const float* W2a   = (const float*)d_in[17];
  const float* W1b   = (const float*)d_in[18];
  const float* W2b   = (const float*)d_in[19];
  const float* W_m1  = (const float*)d_in[20];
  const float* b_m1  = (const float*)d_in[21];
  const float* W_m2  = (const float*)d_in[22];
  const float* b_m2  = (const float*)d_in[23];
  float* out = (float*)d_out;

  if (ws_size >= (size_t)WS_NEED) {
    decoder_kernel_split<<<2*NS, 1024, 0, stream>>>(
        last_pos, last_pos_rel, hh, ch, eg,
        W_se, b_se, Wih, Whh, bih, bhh, W_hp, b_hp, W_pse, b_pse,
        W1a, W2a, W1b, W2b, W_m1, b_m1, W_m2, b_m2, out, (float*)d_ws);
  } else {
    decoder_kernel_mono<<<NS, 1024, 0, stream>>>(
        last_pos, last_pos_rel, hh, ch, eg,
        W_se, b_se, Wih, Whh, bih, bhh, W_hp, b_hp, W_pse, b_pse,
        W1a, W2a, W1b, W2b, W_m1, b_m1, W_m2, b_m2, out);
  }
}

// Round 10
// 305.855 us; speedup vs baseline: 1.4457x; 1.4457x over previous
//
#include <hip/hip_runtime.h>

#define NS 128
#define NP 32
#define HD 32
#define ED 16
#define GH 72
#define GO 8
#define MD 64
#define TT 8
#define NB (NS*NP)

#define SLOT 272   // floats per slot: 256 data + flag + pad
// 256 blocks x 2 parity slots
#define WS_NEED (256*2*SLOT*4)

typedef float v2f __attribute__((ext_vector_type(2)));

__device__ __forceinline__ float sigm(float x){ return 1.0f/(1.0f+__expf(-x)); }
__device__ __forceinline__ float tanhfast(float x){ return 1.0f - 2.0f/(__expf(2.0f*x)+1.0f); }
__device__ __forceinline__ unsigned rne16(float f){
  unsigned u = __float_as_uint(f);
  u += 0x7fffu + ((u>>16)&1u);
  return u>>16;
}
__device__ __forceinline__ float lo16(unsigned v){ return __uint_as_float(v<<16); }
__device__ __forceinline__ float hi16(unsigned v){ return __uint_as_float(v & 0xffff0000u); }

// ==================== split kernel: 256 blocks, (scene, m) per block ====================
__global__ __launch_bounds__(1024, 1) void decoder_kernel_split(
    const float* __restrict__ last_pos, const float* __restrict__ last_pos_rel,
    const float* __restrict__ hh, const float* __restrict__ ch,
    const int*  __restrict__ eg,
    const float* __restrict__ W_se, const float* __restrict__ b_se,
    const float* __restrict__ Wih, const float* __restrict__ Whh,
    const float* __restrict__ bih, const float* __restrict__ bhh,
    const float* __restrict__ W_hp, const float* __restrict__ b_hp,
    const float* __restrict__ W_pse, const float* __restrict__ b_pse,
    const float* __restrict__ W1a, const float* __restrict__ W2a,
    const float* __restrict__ W1b, const float* __restrict__ W2b,
    const float* __restrict__ W_m1, const float* __restrict__ b_m1,
    const float* __restrict__ W_m2, const float* __restrict__ b_m2,
    float* __restrict__ out, float* __restrict__ ws)
{
  const int tid   = threadIdx.x;
  const int scn   = blockIdx.x >> 1;
  const int myM   = blockIdx.x & 1;
  const int lane  = tid & 31;
  const int grp32 = tid >> 5;      // 0..31

  // uni overlays: G[32][128] gate staging (16 KB) <-> a1[32][76] (9.7 KB)
  __shared__ __align__(16) float uni[4096];
  __shared__ __align__(16) unsigned W1p[16][GH];   // own m, bf16 pairs (hk, hk+1)
  __shared__ __align__(16) float W2l[GH][GO];      // own m
  __shared__ __align__(16) float Wp1[2][GH];       // own m
  __shared__ __align__(16) float c1l[GH];          // own m
  __shared__ __align__(16) float hbuf[NP][HD];
  __shared__ __align__(16) float h2buf[NP][36];
  __shared__ __align__(16) float GS[5][GH];        // own m
  __shared__ __align__(16) float phbuf[NP][16];
  __shared__ __align__(16) unsigned Wm1p[48][32];
  __shared__ __align__(16) unsigned Wm2p[32][32];
  __shared__ float lpbuf[NP][2], rpbuf[NP][2], Whp[HD][2];
  __shared__ float bm1l[MD], bm2l[HD], bhp2[2];
  __shared__ unsigned bm[NP];
  __shared__ float invn[NP];
  __shared__ int gl[NP];

  float* const a1 = uni;   // [32][76]

  const int mybase = (scn*2 + myM)*2;       // slot-pair index (x SLOT)
  const int pbase  = (scn*2 + 1 - myM)*2;

  // ---------- persistent per-thread LSTM row weights (global read ONCE) ----------
  const int myrow = tid & 127;
  const int pq4   = tid >> 7;
  float wrow[HD];
  #pragma unroll
  for (int c = 0; c < HD/4; c++) {
    float4 w = *(const float4*)(Whh + myrow*HD + c*4);
    wrow[c*4+0]=w.x; wrow[c*4+1]=w.y; wrow[c*4+2]=w.z; wrow[c*4+3]=w.w;
  }
  float wf0 = 0.f, wf1 = 0.f, bfr = bih[myrow] + bhh[myrow];
  #pragma unroll
  for (int e = 0; e < ED; e++) {
    float wv = Wih[myrow*ED + e];
    wf0 = fmaf(W_se[e],    wv, wf0);
    wf1 = fmaf(W_se[ED+e], wv, wf1);
    bfr = fmaf(b_se[e],    wv, bfr);
  }

  float creg = ch[(scn*NP + grp32)*HD + lane];
  hbuf[grp32][lane] = hh[(scn*NP + grp32)*HD + lane];

  // ---------- setup ----------
  if (tid < NP) {
    int gi = eg[scn*NP + tid];
    gl[tid] = gi;
    unsigned sm = 0;
    for (int j = 0; j < NP; j++) {
      int gj = eg[scn*NP + j];
      bool sj = (j == tid) || (gi == gj && gi != 0);
      sm |= ((unsigned)sj) << j;
    }
    unsigned mk = myM ? ((~sm) | (1u << tid)) : sm;
    bm[tid] = mk;
    invn[tid] = 1.0f/(float)__popc(mk);
  }
  if (tid < 64) {
    int p = tid >> 1, k = tid & 1;
    lpbuf[p][k] = last_pos[(scn*NP+p)*2+k];
    rpbuf[p][k] = last_pos_rel[(scn*NP+p)*2+k];
    Whp[p][k]   = W_hp[tid];
    bm1l[tid]   = b_m1[tid];
  }
  if (tid < 32) bm2l[tid] = b_m2[tid];
  if (tid < 2)  bhp2[tid] = b_hp[tid];
  const float* W1my = myM ? W1b : W1a;
  if (tid < GH) {   // folded Wp1 = W_pse@W1[:16], c1 = b_pse@W1[:16] (own m)
    int d = tid;
    float s0 = 0.f, s1 = 0.f, sc1 = 0.f;
    for (int e = 0; e < ED; e++) {
      float w = W1my[e*GH + d];
      s0  += W_pse[e]    * w;
      s1  += W_pse[ED+e] * w;
      sc1 += b_pse[e]    * w;
    }
    Wp1[0][d] = s0; Wp1[1][d] = s1; c1l[d] = sc1;
  }
  if (tid < GH*GO) {   // W2 own m, fp32 (576)
    W2l[tid/GO][tid%GO] = (myM ? W2b : W2a)[tid];
  }
  #pragma unroll
  for (int r = 0; r < 2; r++) {  // W1p own m, packed bf16 (1152: TWO passes)
    int u = tid + 1024*r;
    if (u < 16*GH) {
      int k2 = u/GH, d = u%GH;
      unsigned lo = rne16(W1my[(ED+2*k2  )*GH + d]);
      unsigned hi = rne16(W1my[(ED+2*k2+1)*GH + d]);
      W1p[k2][d] = lo | (hi << 16);
    }
  }
  #pragma unroll
  for (int r = 0; r < 2; r++) {   // Wm1p packed bf16 (1536)
    int u = tid + 1024*r;
    if (u < 1536) {
      int k = u >> 5, uu = u & 31;
      Wm1p[k][uu] = rne16(W_m1[k*MD + uu]) | (rne16(W_m1[k*MD + 32 + uu]) << 16);
    }
  }
  {  // Wm2p packed bf16 (1024)
    int k = tid >> 5, uu = tid & 31;
    Wm2p[k][uu] = rne16(W_m2[k*HD + uu]) | (rne16(W_m2[(k+32)*HD + uu]) << 16);
  }
  __syncthreads();

  // ---------------- time steps ----------------
  for (int t = 0; t < TT; t++) {
    // P1a: gates[p][myrow] for 4 peds (redundant in both blocks; deterministic)
    {
      float rG[4];
      #pragma unroll
      for (int pp2 = 0; pp2 < 4; pp2++) {
        int p = pq4*4 + pp2;
        float acc = fmaf(rpbuf[p][0], wf0, fmaf(rpbuf[p][1], wf1, bfr));
        #pragma unroll
        for (int c = 0; c < 8; c++) {
          float4 h4 = *(const float4*)&hbuf[p][c*4];
          acc = fmaf(h4.x, wrow[c*4+0], acc);
          acc = fmaf(h4.y, wrow[c*4+1], acc);
          acc = fmaf(h4.z, wrow[c*4+2], acc);
          acc = fmaf(h4.w, wrow[c*4+3], acc);
        }
        rG[pp2] = acc;
      }
      #pragma unroll
      for (int pp2 = 0; pp2 < 4; pp2++) uni[(pq4*4+pp2)*128 + myrow] = rG[pp2];
    }
    __syncthreads();

    // P1b: activations, c/h2 update; rel_pos reduction; out store (m=0 block only)
    {
      int p = grp32, n = lane;
      float gi_ = uni[p*128 +       n];
      float gf_ = uni[p*128 +  32 + n];
      float gg_ = uni[p*128 +  64 + n];
      float go_ = uni[p*128 +  96 + n];
      float c2 = sigm(gf_)*creg + sigm(gi_)*tanhfast(gg_);
      creg = c2;
      float h2 = sigm(go_)*tanhfast(c2);
      h2buf[p][n] = h2;
      float r0 = h2 * Whp[n][0];
      float r1 = h2 * Whp[n][1];
      #pragma unroll
      for (int off = 1; off < 32; off <<= 1) {
        r0 += __shfl_xor(r0, off, 32);
        r1 += __shfl_xor(r1, off, 32);
      }
      r0 += bhp2[0]; r1 += bhp2[1];
      if (n == 0) {
        if (myM == 0) {
          out[t*NB*2 + (scn*NP+p)*2 + 0] = r0;
          out[t*NB*2 + (scn*NP+p)*2 + 1] = r1;
        }
        rpbuf[p][0] = r0;  rpbuf[p][1] = r1;
        lpbuf[p][0] += r0; lpbuf[p][1] += r1;
      }
    }
    __syncthreads();

    // P2: a1[j][d] + GS group sums (own m). j = lane invariant across passes.
    {
      const int j = lane;
      float lpj0 = lpbuf[j][0], lpj1 = lpbuf[j][1];
      float h2row[HD];
      #pragma unroll
      for (int c = 0; c < 8; c++) {
        float4 v = *(const float4*)&h2buf[j][c*4];
        h2row[c*4+0]=v.x; h2row[c*4+1]=v.y; h2row[c*4+2]=v.z; h2row[c*4+3]=v.w;
      }
      #pragma unroll
      for (int r = 0; r < 3; r++) {
        int d = grp32 + 32*r;
        if (d < GH) {
          float pp_ = fmaf(lpj0, Wp1[0][d], lpj1*Wp1[1][d]);
          float av = pp_;
          #pragma unroll
          for (int k2 = 0; k2 < 16; k2++) {
            unsigned v = W1p[k2][d];
            av = fmaf(h2row[2*k2  ], lo16(v), av);
            av = fmaf(h2row[2*k2+1], hi16(v), av);
          }
          a1[j*76 + d] = av;
          int gj = gl[j];
          float tot = av;
          float s1 = (gj==1)?av:0.f, s2=(gj==2)?av:0.f, s3=(gj==3)?av:0.f, s4=(gj==4)?av:0.f;
          #pragma unroll
          for (int off = 1; off < 32; off <<= 1) {
            tot += __shfl_xor(tot, off, 32);
            s1  += __shfl_xor(s1,  off, 32);
            s2  += __shfl_xor(s2,  off, 32);
            s3  += __shfl_xor(s3,  off, 32);
            s4  += __shfl_xor(s4,  off, 32);
          }
          if (j < 5) {
            float v2;
            if (myM == 0) v2 = (j==0)?tot:((j==1)?s1:((j==2)?s2:((j==3)?s3:s4)));
            else          v2 = (j==0)?tot:((j==1)?tot-s1:((j==2)?tot-s2:((j==3)?tot-s3:tot-s4)));
            GS[j][d] = v2;
          }
        }
      }
    }
    __syncthreads();

    // P3: pool (own m). One task per thread: i = grp32, j = lane.
    {
      const int j = lane, i = grp32;
      unsigned bmv = bm[i];
      bool mij = (bmv >> j) & 1u;
      bool diag = (j == i);
      int gi = gl[i];
      float in_ = invn[i];
      const float *p0, *p1; float c0, c1c;
      if (diag) {
        if (myM == 0) { p0 = gi ? &GS[gi][0] : (a1 + i*76); c0 = in_; p1 = a1 + i*76; c1c = 0.f; }
        else          { p0 = &GS[gi][0];                    c0 = in_; p1 = a1 + i*76; c1c = gi ? in_ : 0.f; }
      } else if (mij) { p0 = a1 + j*76; c0 = 0.5f; p1 = a1 + i*76; c1c = 0.5f; }
      else            { p0 = a1 + j*76; c0 = 1.0f; p1 = a1 + j*76; c1c = 0.f; }
      float NL0 = -lpbuf[i][0], NL1 = -lpbuf[i][1];
      v2f qv[4];
      #pragma unroll
      for (int h = 0; h < 4; h++) qv[h] = (v2f){0.f, 0.f};
      for (int d4 = 0; d4 < GH/4; d4++) {
        float4 c14 = *(const float4*)&c1l[d4*4];
        float4 w04 = *(const float4*)&Wp1[0][d4*4];
        float4 w14 = *(const float4*)&Wp1[1][d4*4];
        float4 va  = diag ? *(const float4*)(p0 + d4*4)
                          : *(const float4*)(a1 + j*76 + d4*4);
        float4 vb  = *(const float4*)(p1 + d4*4);
        float ex = fmaf(NL1, w14.x, fmaf(NL0, w04.x, c14.x));
        float ey = fmaf(NL1, w14.y, fmaf(NL0, w04.y, c14.y));
        float ez = fmaf(NL1, w14.z, fmaf(NL0, w04.z, c14.z));
        float ew = fmaf(NL1, w14.w, fmaf(NL0, w04.w, c14.w));
        float tv[4];
        tv[0] = fmaxf(fmaf(c0, va.x, fmaf(c1c, vb.x, ex)), 0.f);
        tv[1] = fmaxf(fmaf(c0, va.y, fmaf(c1c, vb.y, ey)), 0.f);
        tv[2] = fmaxf(fmaf(c0, va.z, fmaf(c1c, vb.z, ez)), 0.f);
        tv[3] = fmaxf(fmaf(c0, va.w, fmaf(c1c, vb.w, ew)), 0.f);
        #pragma unroll
        for (int k = 0; k < 4; k++) {
          const v2f* w2p = (const v2f*)&W2l[d4*4+k][0];
          v2f wA = w2p[0], wB = w2p[1], wC = w2p[2], wD = w2p[3];
          v2f tk = {tv[k], tv[k]};
          qv[0] += tk*wA; qv[1] += tk*wB; qv[2] += tk*wC; qv[3] += tk*wD;
        }
      }
      float q[8];
      #pragma unroll
      for (int h = 0; h < 4; h++) { q[2*h] = qv[h][0]; q[2*h+1] = qv[h][1]; }
      float sq[8];
      #pragma unroll
      for (int o = 0; o < 8; o++) sq[o] = mij ? q[o] : 0.f;
      #pragma unroll
      for (int off = 1; off < 32; off <<= 1) {
        #pragma unroll
        for (int o = 0; o < 8; o++) sq[o] += __shfl_xor(sq[o], off, 32);
      }
      float qd[8];
      #pragma unroll
      for (int o = 0; o < 8; o++) qd[o] = __shfl(q[o], i, 32);
      float F[8];
      if (diag) {
        #pragma unroll
        for (int o = 0; o < 8; o++) F[o] = fmaxf(sq[o]*in_, 0.f);
      } else {
        float scl = mij ? 0.5f : 1.0f;
        #pragma unroll
        for (int o = 0; o < 8; o++)
          F[o] = fmaxf((q[o] + (mij ? qd[o] : 0.f))*scl, 0.f);
      }
      #pragma unroll
      for (int off = 1; off < 32; off <<= 1) {
        #pragma unroll
        for (int o = 0; o < 8; o++) F[o] = fmaxf(F[o], __shfl_xor(F[o], off, 32));
      }
      if (j == 0) {
        #pragma unroll
        for (int o = 0; o < 8; o++) phbuf[i][myM*GO + o] = F[o];
      }
    }
    __syncthreads();

    // ---- exchange (R6 handshake; data via one-way relaxed agent ops, no RMW) ----
    {
      int sl  = (mybase + (t & 1))*SLOT;
      int psl = (pbase  + (t & 1))*SLOT;
      if (tid < 256) {
        int p = tid >> 3, o = tid & 7;
        __hip_atomic_store(ws + sl + tid, phbuf[p][myM*8 + o],
                           __ATOMIC_RELAXED, __HIP_MEMORY_SCOPE_AGENT);
      }
      __syncthreads();   // drains vmcnt in every wave -> data at coherent point
      if (tid == 0) {
        atomicExch((unsigned*)(ws + sl + 256), (unsigned)(t + 1));
        while (atomicAdd((unsigned*)(ws + psl + 256), 0u) != (unsigned)(t + 1))
          __builtin_amdgcn_s_sleep(2);
      }
      __syncthreads();
      if (tid < 256) {
        int p = tid >> 3, o = tid & 7;
        phbuf[p][(1-myM)*8 + o] =
            __hip_atomic_load(ws + psl + tid, __ATOMIC_RELAXED, __HIP_MEMORY_SCOPE_AGENT);
      }
    }
    __syncthreads();

    // P4: mlp (48 -> 64 -> 32, relu both). 32 lanes per ped (redundant in both blocks).
    {
      int p = grp32, u = lane;
      float in48[48];
      #pragma unroll
      for (int c = 0; c < 8; c++) {
        float4 v = *(const float4*)&h2buf[p][c*4];
        in48[c*4+0]=v.x; in48[c*4+1]=v.y; in48[c*4+2]=v.z; in48[c*4+3]=v.w;
      }
      #pragma unroll
      for (int c = 0; c < 4; c++) {
        float4 v = *(const float4*)&phbuf[p][c*4];
        in48[32+c*4+0]=v.x; in48[32+c*4+1]=v.y; in48[32+c*4+2]=v.z; in48[32+c*4+3]=v.w;
      }
      float m1lo = bm1l[u], m1hi = bm1l[32 + u];
      #pragma unroll
      for (int k = 0; k < 48; k++) {
        unsigned v = Wm1p[k][u];
        m1lo = fmaf(in48[k], lo16(v), m1lo);
        m1hi = fmaf(in48[k], hi16(v), m1hi);
      }
      m1lo = fmaxf(m1lo, 0.f); m1hi = fmaxf(m1hi, 0.f);
      float acc = bm2l[u];
      #pragma unroll
      for (int k = 0; k < 32; k++) {
        unsigned v = Wm2p[k][u];
        acc = fmaf(__shfl(m1lo, k, 32), lo16(v), acc);
        acc = fmaf(__shfl(m1hi, k, 32), hi16(v), acc);
      }
      hbuf[p][u] = fmaxf(acc, 0.f);
    }
    __syncthreads();
  }
}

// ==================== mono fallback: 128 blocks (R4/R6 kernel, verified) ====================
__global__ __launch_bounds__(1024, 1) void decoder_kernel_mono(
    const float* __restrict__ last_pos, const float* __restrict__ last_pos_rel,
    const float* __restrict__ hh, const float* __restrict__ ch,
    const int*  __restrict__ eg,
    const float* __restrict__ W_se, const float* __restrict__ b_se,
    const float* __restrict__ Wih, const float* __restrict__ Whh,
    const float* __restrict__ bih, const float* __restrict__ bhh,
    const float* __restrict__ W_hp, const float* __restrict__ b_hp,
    const float* __restrict__ W_pse, const float* __restrict__ b_pse,
    const float* __restrict__ W1a, const float* __restrict__ W2a,
    const float* __restrict__ W1b, const float* __restrict__ W2b,
    const float* __restrict__ W_m1, const float* __restrict__ b_m1,
    const float* __restrict__ W_m2, const float* __restrict__ b_m2,
    float* __restrict__ out)
{
  const int tid   = threadIdx.x;
  const int scn   = blockIdx.x;
  const int lane  = tid & 31;
  const int grp32 = tid >> 5;

  __shared__ __align__(16) float uni[4864];
  __shared__ __align__(16) unsigned W1p[2][16][GH];
  __shared__ __align__(16) float W2l[2][GH][GO];
  __shared__ __align__(16) float Wp1[2][2][GH];
  __shared__ __align__(16) float c1l[2][GH];
  __shared__ __align__(16) float hbuf[NP][HD];
  __shared__ __align__(16) float h2buf[NP][36];
  __shared__ __align__(16) float GS[2][5][GH];
  __shared__ __align__(16) float phbuf[NP][16];
  __shared__ __align__(16) unsigned Wm1p[48][32];
  __shared__ __align__(16) unsigned Wm2p[32][32];
  __shared__ float lpbuf[NP][2], rpbuf[NP][2], Whp[HD][2];
  __shared__ float bm1l[MD], bm2l[HD], bhp2[2];
  __shared__ unsigned bm[2][NP];
  __shared__ float invn[2][NP];
  __shared__ int gl[NP];

  const int myrow = tid & 127;
  const int pq4   = tid >> 7;
  float wrow[HD];
  #pragma unroll
  for (int c = 0; c < HD/4; c++) {
    float4 w = *(const float4*)(Whh + myrow*HD + c*4);
    wrow[c*4+0]=w.x; wrow[c*4+1]=w.y; wrow[c*4+2]=w.z; wrow[c*4+3]=w.w;
  }
  float wf0 = 0.f, wf1 = 0.f, bfr = bih[myrow] + bhh[myrow];
  #pragma unroll
  for (int e = 0; e < ED; e++) {
    float wv = Wih[myrow*ED + e];
    wf0 = fmaf(W_se[e],    wv, wf0);
    wf1 = fmaf(W_se[ED+e], wv, wf1);
    bfr = fmaf(b_se[e],    wv, bfr);
  }
  float creg = ch[(scn*NP + grp32)*HD + lane];
  hbuf[grp32][lane] = hh[(scn*NP + grp32)*HD + lane];

  if (tid < NP) {
    int gi = eg[scn*NP + tid];
    gl[tid] = gi;
    unsigned sm = 0;
    for (int j = 0; j < NP; j++) {
      int gj = eg[scn*NP + j];
      bool sj = (j == tid) || (gi == gj && gi != 0);
      sm |= ((unsigned)sj) << j;
    }
    unsigned dm = (~sm) | (1u << tid);
    bm[0][tid] = sm; bm[1][tid] = dm;
    invn[0][tid] = 1.0f/(float)__popc(sm);
    invn[1][tid] = 1.0f/(float)__popc(dm);
  }
  if (tid < 64) {
    int p = tid >> 1, k = tid & 1;
    lpbuf[p][k] = last_pos[(scn*NP+p)*2+k];
    rpbuf[p][k] = last_pos_rel[(scn*NP+p)*2+k];
    Whp[p][k]   = W_hp[tid];
    bm1l[tid]   = b_m1[tid];
  }
  if (tid < 32) bm2l[tid] = b_m2[tid];
  if (tid < 2)  bhp2[tid] = b_hp[tid];
  if (tid < 2*GH) {
    int m = tid / GH, d = tid % GH;
    const float* W1 = m ? W1b : W1a;
    float s0 = 0.f, s1 = 0.f, sc1 = 0.f;
    for (int e = 0; e < ED; e++) {
      float w = W1[e*GH + d];
      s0 += W_pse[e]*w; s1 += W_pse[ED+e]*w; sc1 += b_pse[e]*w;
    }
    Wp1[m][0][d] = s0; Wp1[m][1][d] = s1; c1l[m][d] = sc1;
  }
  {
    int u = tid;
    if (u < 2*GH*GO) {
      int m = u/(GH*GO), rest = u%(GH*GO);
      W2l[m][rest/GO][rest%GO] = (m ? W2b : W2a)[rest];
    }
    if (tid < 128) {
      int u2 = tid + 1024;
      int m = u2/(GH*GO), rest = u2%(GH*GO);
      W2l[m][rest/GO][rest%GO] = (m ? W2b : W2a)[rest];
    }
  }
  #pragma unroll
  for (int r = 0; r < 3; r++) {
    int u = tid + 1024*r;
    if (u < 2304) {
      int m = u/1152, rest = u%1152, k2 = rest/GH, d = rest%GH;
      const float* W1 = m ? W1b : W1a;
      W1p[m][k2][d] = rne16(W1[(ED+2*k2)*GH + d]) | (rne16(W1[(ED+2*k2+1)*GH + d]) << 16);
    }
  }
  #pragma unroll
  for (int r = 0; r < 2; r++) {
    int u = tid + 1024*r;
    if (u < 1536) {
      int k = u >> 5, uu = u & 31;
      Wm1p[k][uu] = rne16(W_m1[k*MD + uu]) | (rne16(W_m1[k*MD + 32 + uu]) << 16);
    }
  }
  {
    int k = tid >> 5, uu = tid & 31;
    Wm2p[k][uu] = rne16(W_m2[k*HD + uu]) | (rne16(W_m2[(k+32)*HD + uu]) << 16);
  }
  __syncthreads();

  for (int t = 0; t < TT; t++) {
    {
      float rG[4];
      #pragma unroll
      for (int pp2 = 0; pp2 < 4; pp2++) {
        int p = pq4*4 + pp2;
        float acc = fmaf(rpbuf[p][0], wf0, fmaf(rpbuf[p][1], wf1, bfr));
        #pragma unroll
        for (int c = 0; c < 8; c++) {
          float4 h4 = *(const float4*)&hbuf[p][c*4];
          acc = fmaf(h4.x, wrow[c*4+0], acc);
          acc = fmaf(h4.y, wrow[c*4+1], acc);
          acc = fmaf(h4.z, wrow[c*4+2], acc);
          acc = fmaf(h4.w, wrow[c*4+3], acc);
        }
        rG[pp2] = acc;
      }
      #pragma unroll
      for (int pp2 = 0; pp2 < 4; pp2++) uni[(pq4*4+pp2)*128 + myrow] = rG[pp2];
    }
    __syncthreads();
    {
      int p = grp32, n = lane;
      float gi_ = uni[p*128 + n];
      float gf_ = uni[p*128 + 32 + n];
      float gg_ = uni[p*128 + 64 + n];
      float go_ = uni[p*128 + 96 + n];
      float c2 = sigm(gf_)*creg + sigm(gi_)*tanhfast(gg_);
      creg = c2;
      float h2 = sigm(go_)*tanhfast(c2);
      h2buf[p][n] = h2;
      float r0 = h2 * Whp[n][0];
      float r1 = h2 * Whp[n][1];
      #pragma unroll
      for (int off = 1; off < 32; off <<= 1) {
        r0 += __shfl_xor(r0, off, 32);
        r1 += __shfl_xor(r1, off, 32);
      }
      r0 += bhp2[0]; r1 += bhp2[1];
      if (n == 0) {
        out[t*NB*2 + (scn*NP+p)*2 + 0] = r0;
        out[t*NB*2 + (scn*NP+p)*2 + 1] = r1;
        rpbuf[p][0] = r0;  rpbuf[p][1] = r1;
        lpbuf[p][0] += r0; lpbuf[p][1] += r1;
      }
    }
    __syncthreads();
    {
      const int j = lane;
      float lpj0 = lpbuf[j][0], lpj1 = lpbuf[j][1];
      float h2row[HD];
      #pragma unroll
      for (int c = 0; c < 8; c++) {
        float4 v = *(const float4*)&h2buf[j][c*4];
        h2row[c*4+0]=v.x; h2row[c*4+1]=v.y; h2row[c*4+2]=v.z; h2row[c*4+3]=v.w;
      }
      #pragma unroll
      for (int r = 0; r < 5; r++) {
        int rest = grp32 + 32*r;
        if (rest < 144) {
          int m = rest >= 72 ? 1 : 0;
          int d = rest - 72*m;
          float pp_ = fmaf(lpj0, Wp1[m][0][d], lpj1*Wp1[m][1][d]);
          float av = pp_;
          #pragma unroll
          for (int k2 = 0; k2 < 16; k2++) {
            unsigned v = W1p[m][k2][d];
            av = fmaf(h2row[2*k2], lo16(v), av);
            av = fmaf(h2row[2*k2+1], hi16(v), av);
          }
          uni[m*2432 + j*76 + d] = av;
          int gj = gl[j];
          float tot = av;
          float s1 = (gj==1)?av:0.f, s2=(gj==2)?av:0.f, s3=(gj==3)?av:0.f, s4=(gj==4)?av:0.f;
          #pragma unroll
          for (int off = 1; off < 32; off <<= 1) {
            tot += __shfl_xor(tot, off, 32);
            s1 += __shfl_xor(s1, off, 32);
            s2 += __shfl_xor(s2, off, 32);
            s3 += __shfl_xor(s3, off, 32);
            s4 += __shfl_xor(s4, off, 32);
          }
          if (j < 5) {
            float v2;
            if (m == 0) v2 = (j==0)?tot:((j==1)?s1:((j==2)?s2:((j==3)?s3:s4)));
            else        v2 = (j==0)?tot:((j==1)?tot-s1:((j==2)?tot-s2:((j==3)?tot-s3:tot-s4)));
            GS[m][j][d] = v2;
          }
        }
      }
    }
    __syncthreads();
    {
      const int j   = lane;
      const int m   = tid >> 9;
      const int sub = (tid >> 5) & 15;
      const float* am = uni + m*2432;
      int   I2[2] = {sub, sub + 16};
      const float *P0[2], *P1[2];
      float C0[2], C1[2], NL0[2], NL1[2];
      bool  MIJ[2], DIAG[2];
      v2f qv[2][4];
      #pragma unroll
      for (int r = 0; r < 2; r++) {
        int i = I2[r];
        unsigned bmv = bm[m][i];
        bool mij = (bmv >> j) & 1u;
        bool diag = (j == i);
        int gi = gl[i];
        float in_ = invn[m][i];
        const float *p0, *p1; float c0, c1c;
        if (diag) {
          if (m == 0) { p0 = gi ? &GS[0][gi][0] : (am + i*76); c0 = in_; p1 = am + i*76; c1c = 0.f; }
          else        { p0 = &GS[1][gi][0];                    c0 = in_; p1 = am + i*76; c1c = gi ? in_ : 0.f; }
        } else if (mij) { p0 = am + j*76; c0 = 0.5f; p1 = am + i*76; c1c = 0.5f; }
        else            { p0 = am + j*76; c0 = 1.0f; p1 = am + j*76; c1c = 0.f; }
        P0[r]=p0; P1[r]=p1; C0[r]=c0; C1[r]=c1c; MIJ[r]=mij; DIAG[r]=diag;
        NL0[r] = -lpbuf[i][0]; NL1[r] = -lpbuf[i][1];
        #pragma unroll
        for (int h = 0; h < 4; h++) qv[r][h] = (v2f){0.f, 0.f};
      }
      for (int d4 = 0; d4 < GH/4; d4++) {
        float4 c14 = *(const float4*)&c1l[m][d4*4];
        float4 w04 = *(const float4*)&Wp1[m][0][d4*4];
        float4 w14 = *(const float4*)&Wp1[m][1][d4*4];
        float4 vaS = *(const float4*)(am + j*76 + d4*4);
        float4 va0 = vaS, va1 = vaS;
        if (DIAG[0]) va0 = *(const float4*)(P0[0] + d4*4);
        if (DIAG[1]) va1 = *(const float4*)(P0[1] + d4*4);
        float4 vb0 = *(const float4*)(P1[0] + d4*4);
        float4 vb1 = *(const float4*)(P1[1] + d4*4);
        float e0x = fmaf(NL1[0], w14.x, fmaf(NL0[0], w04.x, c14.x));
        float e0y = fmaf(NL1[0], w14.y, fmaf(NL0[0], w04.y, c14.y));
        float e0z = fmaf(NL1[0], w14.z, fmaf(NL0[0], w04.z, c14.z));
        float e0w = fmaf(NL1[0], w14.w, fmaf(NL0[0], w04.w, c14.w));
        float e1x = fmaf(NL1[1], w14.x, fmaf(NL0[1], w04.x, c14.x));
        float e1y = fmaf(NL1[1], w14.y, fmaf(NL0[1], w04.y, c14.y));
        float e1z = fmaf(NL1[1], w14.z, fmaf(NL0[1], w04.z, c14.z));
        float e1w = fmaf(NL1[1], w14.w, fmaf(NL0[1], w04.w, c14.w));
        float tv0[4], tv1[4];
        tv0[0] = fmaxf(fmaf(C0[0], va0.x, fmaf(C1[0], vb0.x, e0x)), 0.f);
        tv0[1] = fmaxf(fmaf(C0[0], va0.y, fmaf(C1[0], vb0.y, e0y)), 0.f);
        tv0[2] = fmaxf(fmaf(C0[0], va0.z, fmaf(C1[0], vb0.z, e0z)), 0.f);
        tv0[3] = fmaxf(fmaf(C0[0], va0.w, fmaf(C1[0], vb0.w, e0w)), 0.f);
        tv1[0] = fmaxf(fmaf(C0[1], va1.x, fmaf(C1[1], vb1.x, e1x)), 0.f);
        tv1[1] = fmaxf(fmaf(C0[1], va1.y, fmaf(C1[1], vb1.y, e1y)), 0.f);
        tv1[2] = fmaxf(fmaf(C0[1], va1.z, fmaf(C1[1], vb1.z, e1z)), 0.f);
        tv1[3] = fmaxf(fmaf(C0[1], va1.w, fmaf(C1[1], vb1.w, e1w)), 0.f);
        #pragma unroll
        for (int k = 0; k < 4; k++) {
          const v2f* w2p = (const v2f*)&W2l[m][d4*4+k][0];
          v2f wA = w2p[0], wB = w2p[1], wC = w2p[2], wD = w2p[3];
          v2f t0 = {tv0[k], tv0[k]};
          qv[0][0] += t0*wA; qv[0][1] += t0*wB; qv[0][2] += t0*wC; qv[0][3] += t0*wD;
          v2f t1 = {tv1[k], tv1[k]};
          qv[1][0] += t1*wA; qv[1][1] += t1*wB; qv[1][2] += t1*wC; qv[1][3] += t1*wD;
        }
      }
      #pragma unroll
      for (int r = 0; r < 2; r++) {
        float q[8];
        #pragma unroll
        for (int h = 0; h < 4; h++) { q[2*h] = qv[r][h][0]; q[2*h+1] = qv[r][h][1]; }
        float sq[8];
        #pragma unroll
        for (int o = 0; o < 8; o++) sq[o] = MIJ[r] ? q[o] : 0.f;
        #pragma unroll
        for (int off = 1; off < 32; off <<= 1) {
          #pragma unroll
          for (int o = 0; o < 8; o++) sq[o] += __shfl_xor(sq[o], off, 32);
        }
        float qd[8];
        #pragma unroll
        for (int o = 0; o < 8; o++) qd[o] = __shfl(q[o], I2[r], 32);
        float in_ = invn[m][I2[r]];
        float F[8];
        if (DIAG[r]) {
          #pragma unroll
          for (int o = 0; o < 8; o++) F[o] = fmaxf(sq[o]*in_, 0.f);
        } else {
          float scl = MIJ[r] ? 0.5f : 1.0f;
          #pragma unroll
          for (int o = 0; o < 8; o++)
            F[o] = fmaxf((q[o] + (MIJ[r] ? qd[o] : 0.f))*scl, 0.f);
        }
        #pragma unroll
        for (int off = 1; off < 32; off <<= 1) {
          #pragma unroll
          for (int o = 0; o < 8; o++) F[o] = fmaxf(F[o], __shfl_xor(F[o], off, 32));
        }
        if (j == 0) {
          #pragma unroll
          for (int o = 0; o < 8; o++) phbuf[I2[r]][m*GO + o] = F[o];
        }
      }
    }
    __syncthreads();
    {
      int p = grp32, u = lane;
      float in48[48];
      #pragma unroll
      for (int c = 0; c < 8; c++) {
        float4 v = *(const float4*)&h2buf[p][c*4];
        in48[c*4+0]=v.x; in48[c*4+1]=v.y; in48[c*4+2]=v.z; in48[c*4+3]=v.w;
      }
      #pragma unroll
      for (int c = 0; c < 4; c++) {
        float4 v = *(const float4*)&phbuf[p][c*4];
        in48[32+c*4+0]=v.x; in48[32+c*4+1]=v.y; in48[32+c*4+2]=v.z; in48[32+c*4+3]=v.w;
      }
      float m1lo = bm1l[u], m1hi = bm1l[32 + u];
      #pragma unroll
      for (int k = 0; k < 48; k++) {
        unsigned v = Wm1p[k][u];
        m1lo = fmaf(in48[k], lo16(v), m1lo);
        m1hi = fmaf(in48[k], hi16(v), m1hi);
      }
      m1lo = fmaxf(m1lo, 0.f); m1hi = fmaxf(m1hi, 0.f);
      float acc = bm2l[u];
      #pragma unroll
      for (int k = 0; k < 32; k++) {
        unsigned v = Wm2p[k][u];
        acc = fmaf(__shfl(m1lo, k, 32), lo16(v), acc);
        acc = fmaf(__shfl(m1hi, k, 32), hi16(v), acc);
      }
      hbuf[p][u] = fmaxf(acc, 0.f);
    }
    __syncthreads();
  }
}

extern "C" void kernel_launch(void* const* d_in, const int* in_sizes, int n_in,
                              void* d_out, int out_size, void* d_ws, size_t ws_size,
                              hipStream_t stream) {
  (void)in_sizes; (void)n_in; (void)out_size;
  const float* last_pos     = (const float*)d_in[0];
  const float* last_pos_rel = (const float*)d_in[1];
  const float* hh           = (const float*)d_in[2];
  const float* ch           = (const float*)d_in[3];
  const int*  eg            = (const int*) d_in[5];
  const float* W_se  = (const float*)d_in[6];
  const float* b_se  = (const float*)d_in[7];
  const float* Wih   = (const float*)d_in[8];
  const float* Whh   = (const float*)d_in[9];
  const float* bih   = (const float*)d_in[10];
  const float* bhh   = (const float*)d_in[11];
  const float* W_hp  = (const float*)d_in[12];
  const float* b_hp  = (const float*)d_in[13];
  const float* W_pse = (const float*)d_in[14];
  const float* b_pse = (const float*)d_in[15];
  const float* W1a   = (const float*)d_in[16];
  const float* W2a   = (const float*)d_in[17];
  const float* W1b   = (const float*)d_in[18];
  const float* W2b   = (const float*)d_in[19];
  const float* W_m1  = (const float*)d_in[20];
  const float* b_m1  = (const float*)d_in[21];
  const float* W_m2  = (const float*)d_in[22];
  const float* b_m2  = (const float*)d_in[23];
  float* out = (float*)d_out;

  if (ws_size >= (size_t)WS_NEED) {
    decoder_kernel_split<<<2*NS, 1024, 0, stream>>>(
        last_pos, last_pos_rel, hh, ch, eg,
        W_se, b_se, Wih, Whh, bih, bhh, W_hp, b_hp, W_pse, b_pse,
        W1a, W2a, W1b, W2b, W_m1, b_m1, W_m2, b_m2, out, (float*)d_ws);
  } else {
    decoder_kernel_mono<<<NS, 1024, 0, stream>>>(
        last_pos, last_pos_rel, hh, ch, eg,
        W_se, b_se, Wih, Whh, bih, bhh, W_hp, b_hp, W_pse, b_pse,
        W1a, W2a, W1b, W2b, W_m1, b_m1, W_m2, b_m2, out);
  }
}

// Round 11
// 301.075 us; speedup vs baseline: 1.4686x; 1.0159x over previous
//
#include <hip/hip_runtime.h>

#define NS 128
#define NP 32
#define HD 32
#define ED 16
#define GH 72
#define GO 8
#define MD 64
#define TT 8
#define NB (NS*NP)

#define SLOT 272   // floats per slot: 256 data + flag + pad
// 256 blocks x 2 parity slots
#define WS_NEED (256*2*SLOT*4)

typedef float v2f __attribute__((ext_vector_type(2)));

__device__ __forceinline__ float sigm(float x){ return 1.0f/(1.0f+__expf(-x)); }
__device__ __forceinline__ float tanhfast(float x){ return 1.0f - 2.0f/(__expf(2.0f*x)+1.0f); }
__device__ __forceinline__ unsigned rne16(float f){
  unsigned u = __float_as_uint(f);
  u += 0x7fffu + ((u>>16)&1u);
  return u>>16;
}
__device__ __forceinline__ float lo16(unsigned v){ return __uint_as_float(v<<16); }
__device__ __forceinline__ float hi16(unsigned v){ return __uint_as_float(v & 0xffff0000u); }

// ==================== split kernel: 256 blocks, (scene, m) per block ====================
__global__ __launch_bounds__(1024, 1) void decoder_kernel_split(
    const float* __restrict__ last_pos, const float* __restrict__ last_pos_rel,
    const float* __restrict__ hh, const float* __restrict__ ch,
    const int*  __restrict__ eg,
    const float* __restrict__ W_se, const float* __restrict__ b_se,
    const float* __restrict__ Wih, const float* __restrict__ Whh,
    const float* __restrict__ bih, const float* __restrict__ bhh,
    const float* __restrict__ W_hp, const float* __restrict__ b_hp,
    const float* __restrict__ W_pse, const float* __restrict__ b_pse,
    const float* __restrict__ W1a, const float* __restrict__ W2a,
    const float* __restrict__ W1b, const float* __restrict__ W2b,
    const float* __restrict__ W_m1, const float* __restrict__ b_m1,
    const float* __restrict__ W_m2, const float* __restrict__ b_m2,
    float* __restrict__ out, float* __restrict__ ws)
{
  const int tid   = threadIdx.x;
  // XCD-pair swizzle: partners (scn, m=0/1) are blockIdx b and b^8 -> same XCD
  // under round-robin dispatch (xcd = blockIdx % 8 on 8-XCD MI355X). Perf-only relabel.
  const int bid   = blockIdx.x;
  const int scn   = (bid & 7) | ((bid >> 4) << 3);
  const int myM   = (bid >> 3) & 1;
  const int lane  = tid & 31;
  const int grp32 = tid >> 5;      // 0..31

  // uni overlays: G[32][128] gate staging (16 KB) <-> a1[32][76] (9.7 KB)
  __shared__ __align__(16) float uni[4096];
  __shared__ __align__(16) unsigned W1p[16][GH];   // own m, bf16 pairs (hk, hk+1)
  __shared__ __align__(16) float W2l[GH][GO];      // own m
  __shared__ __align__(16) float Wp1[2][GH];       // own m
  __shared__ __align__(16) float c1l[GH];          // own m
  __shared__ __align__(16) float hbuf[NP][HD];
  __shared__ __align__(16) float h2buf[NP][36];
  __shared__ __align__(16) float GS[5][GH];        // own m
  __shared__ __align__(16) float phbuf[NP][16];
  __shared__ __align__(16) unsigned Wm1p[48][32];
  __shared__ __align__(16) unsigned Wm2p[32][32];
  __shared__ float lpbuf[NP][2], rpbuf[NP][2], Whp[HD][2];
  __shared__ float bm1l[MD], bm2l[HD], bhp2[2];
  __shared__ unsigned bm[NP];
  __shared__ float invn[NP];
  __shared__ int gl[NP];

  float* const a1 = uni;   // [32][76]

  const int mybase = (scn*2 + myM)*2;       // slot-pair index (x SLOT)
  const int pbase  = (scn*2 + 1 - myM)*2;

  // ---------- persistent per-thread LSTM row weights (global read ONCE) ----------
  const int myrow = tid & 127;
  const int pq4   = tid >> 7;
  float wrow[HD];
  #pragma unroll
  for (int c = 0; c < HD/4; c++) {
    float4 w = *(const float4*)(Whh + myrow*HD + c*4);
    wrow[c*4+0]=w.x; wrow[c*4+1]=w.y; wrow[c*4+2]=w.z; wrow[c*4+3]=w.w;
  }
  float wf0 = 0.f, wf1 = 0.f, bfr = bih[myrow] + bhh[myrow];
  #pragma unroll
  for (int e = 0; e < ED; e++) {
    float wv = Wih[myrow*ED + e];
    wf0 = fmaf(W_se[e],    wv, wf0);
    wf1 = fmaf(W_se[ED+e], wv, wf1);
    bfr = fmaf(b_se[e],    wv, bfr);
  }

  float creg = ch[(scn*NP + grp32)*HD + lane];
  hbuf[grp32][lane] = hh[(scn*NP + grp32)*HD + lane];

  // ---------- setup ----------
  if (tid < NP) {
    int gi = eg[scn*NP + tid];
    gl[tid] = gi;
    unsigned sm = 0;
    for (int j = 0; j < NP; j++) {
      int gj = eg[scn*NP + j];
      bool sj = (j == tid) || (gi == gj && gi != 0);
      sm |= ((unsigned)sj) << j;
    }
    unsigned mk = myM ? ((~sm) | (1u << tid)) : sm;
    bm[tid] = mk;
    invn[tid] = 1.0f/(float)__popc(mk);
  }
  if (tid < 64) {
    int p = tid >> 1, k = tid & 1;
    lpbuf[p][k] = last_pos[(scn*NP+p)*2+k];
    rpbuf[p][k] = last_pos_rel[(scn*NP+p)*2+k];
    Whp[p][k]   = W_hp[tid];
    bm1l[tid]   = b_m1[tid];
  }
  if (tid < 32) bm2l[tid] = b_m2[tid];
  if (tid < 2)  bhp2[tid] = b_hp[tid];
  const float* W1my = myM ? W1b : W1a;
  if (tid < GH) {   // folded Wp1 = W_pse@W1[:16], c1 = b_pse@W1[:16] (own m)
    int d = tid;
    float s0 = 0.f, s1 = 0.f, sc1 = 0.f;
    for (int e = 0; e < ED; e++) {
      float w = W1my[e*GH + d];
      s0  += W_pse[e]    * w;
      s1  += W_pse[ED+e] * w;
      sc1 += b_pse[e]    * w;
    }
    Wp1[0][d] = s0; Wp1[1][d] = s1; c1l[d] = sc1;
  }
  if (tid < GH*GO) {   // W2 own m, fp32 (576)
    W2l[tid/GO][tid%GO] = (myM ? W2b : W2a)[tid];
  }
  #pragma unroll
  for (int r = 0; r < 2; r++) {  // W1p own m, packed bf16 (1152: TWO passes)
    int u = tid + 1024*r;
    if (u < 16*GH) {
      int k2 = u/GH, d = u%GH;
      unsigned lo = rne16(W1my[(ED+2*k2  )*GH + d]);
      unsigned hi = rne16(W1my[(ED+2*k2+1)*GH + d]);
      W1p[k2][d] = lo | (hi << 16);
    }
  }
  #pragma unroll
  for (int r = 0; r < 2; r++) {   // Wm1p packed bf16 (1536)
    int u = tid + 1024*r;
    if (u < 1536) {
      int k = u >> 5, uu = u & 31;
      Wm1p[k][uu] = rne16(W_m1[k*MD + uu]) | (rne16(W_m1[k*MD + 32 + uu]) << 16);
    }
  }
  {  // Wm2p packed bf16 (1024)
    int k = tid >> 5, uu = tid & 31;
    Wm2p[k][uu] = rne16(W_m2[k*HD + uu]) | (rne16(W_m2[(k+32)*HD + uu]) << 16);
  }
  __syncthreads();

  // ---------------- time steps ----------------
  for (int t = 0; t < TT; t++) {
    // P1a: gates[p][myrow] for 4 peds (redundant in both blocks; deterministic)
    {
      float rG[4];
      #pragma unroll
      for (int pp2 = 0; pp2 < 4; pp2++) {
        int p = pq4*4 + pp2;
        float acc = fmaf(rpbuf[p][0], wf0, fmaf(rpbuf[p][1], wf1, bfr));
        #pragma unroll
        for (int c = 0; c < 8; c++) {
          float4 h4 = *(const float4*)&hbuf[p][c*4];
          acc = fmaf(h4.x, wrow[c*4+0], acc);
          acc = fmaf(h4.y, wrow[c*4+1], acc);
          acc = fmaf(h4.z, wrow[c*4+2], acc);
          acc = fmaf(h4.w, wrow[c*4+3], acc);
        }
        rG[pp2] = acc;
      }
      #pragma unroll
      for (int pp2 = 0; pp2 < 4; pp2++) uni[(pq4*4+pp2)*128 + myrow] = rG[pp2];
    }
    __syncthreads();

    // P1b: activations, c/h2 update; rel_pos reduction; out store (m=0 block only)
    {
      int p = grp32, n = lane;
      float gi_ = uni[p*128 +       n];
      float gf_ = uni[p*128 +  32 + n];
      float gg_ = uni[p*128 +  64 + n];
      float go_ = uni[p*128 +  96 + n];
      float c2 = sigm(gf_)*creg + sigm(gi_)*tanhfast(gg_);
      creg = c2;
      float h2 = sigm(go_)*tanhfast(c2);
      h2buf[p][n] = h2;
      float r0 = h2 * Whp[n][0];
      float r1 = h2 * Whp[n][1];
      #pragma unroll
      for (int off = 1; off < 32; off <<= 1) {
        r0 += __shfl_xor(r0, off, 32);
        r1 += __shfl_xor(r1, off, 32);
      }
      r0 += bhp2[0]; r1 += bhp2[1];
      if (n == 0) {
        if (myM == 0) {
          out[t*NB*2 + (scn*NP+p)*2 + 0] = r0;
          out[t*NB*2 + (scn*NP+p)*2 + 1] = r1;
        }
        rpbuf[p][0] = r0;  rpbuf[p][1] = r1;
        lpbuf[p][0] += r0; lpbuf[p][1] += r1;
      }
    }
    __syncthreads();

    // P2: a1[j][d] + GS group sums (own m). j = lane invariant across passes.
    {
      const int j = lane;
      float lpj0 = lpbuf[j][0], lpj1 = lpbuf[j][1];
      float h2row[HD];
      #pragma unroll
      for (int c = 0; c < 8; c++) {
        float4 v = *(const float4*)&h2buf[j][c*4];
        h2row[c*4+0]=v.x; h2row[c*4+1]=v.y; h2row[c*4+2]=v.z; h2row[c*4+3]=v.w;
      }
      #pragma unroll
      for (int r = 0; r < 3; r++) {
        int d = grp32 + 32*r;
        if (d < GH) {
          float pp_ = fmaf(lpj0, Wp1[0][d], lpj1*Wp1[1][d]);
          float av = pp_;
          #pragma unroll
          for (int k2 = 0; k2 < 16; k2++) {
            unsigned v = W1p[k2][d];
            av = fmaf(h2row[2*k2  ], lo16(v), av);
            av = fmaf(h2row[2*k2+1], hi16(v), av);
          }
          a1[j*76 + d] = av;
          int gj = gl[j];
          float tot = av;
          float s1 = (gj==1)?av:0.f, s2=(gj==2)?av:0.f, s3=(gj==3)?av:0.f, s4=(gj==4)?av:0.f;
          #pragma unroll
          for (int off = 1; off < 32; off <<= 1) {
            tot += __shfl_xor(tot, off, 32);
            s1  += __shfl_xor(s1,  off, 32);
            s2  += __shfl_xor(s2,  off, 32);
            s3  += __shfl_xor(s3,  off, 32);
            s4  += __shfl_xor(s4,  off, 32);
          }
          if (j < 5) {
            float v2;
            if (myM == 0) v2 = (j==0)?tot:((j==1)?s1:((j==2)?s2:((j==3)?s3:s4)));
            else          v2 = (j==0)?tot:((j==1)?tot-s1:((j==2)?tot-s2:((j==3)?tot-s3:tot-s4)));
            GS[j][d] = v2;
          }
        }
      }
    }
    __syncthreads();

    // P3: pool (own m). One task per thread: i = grp32, j = lane.
    {
      const int j = lane, i = grp32;
      unsigned bmv = bm[i];
      bool mij = (bmv >> j) & 1u;
      bool diag = (j == i);
      int gi = gl[i];
      float in_ = invn[i];
      const float *p0, *p1; float c0, c1c;
      if (diag) {
        if (myM == 0) { p0 = gi ? &GS[gi][0] : (a1 + i*76); c0 = in_; p1 = a1 + i*76; c1c = 0.f; }
        else          { p0 = &GS[gi][0];                    c0 = in_; p1 = a1 + i*76; c1c = gi ? in_ : 0.f; }
      } else if (mij) { p0 = a1 + j*76; c0 = 0.5f; p1 = a1 + i*76; c1c = 0.5f; }
      else            { p0 = a1 + j*76; c0 = 1.0f; p1 = a1 + j*76; c1c = 0.f; }
      float NL0 = -lpbuf[i][0], NL1 = -lpbuf[i][1];
      v2f qv[4];
      #pragma unroll
      for (int h = 0; h < 4; h++) qv[h] = (v2f){0.f, 0.f};
      for (int d4 = 0; d4 < GH/4; d4++) {
        float4 c14 = *(const float4*)&c1l[d4*4];
        float4 w04 = *(const float4*)&Wp1[0][d4*4];
        float4 w14 = *(const float4*)&Wp1[1][d4*4];
        float4 va  = diag ? *(const float4*)(p0 + d4*4)
                          : *(const float4*)(a1 + j*76 + d4*4);
        float4 vb  = *(const float4*)(p1 + d4*4);
        float ex = fmaf(NL1, w14.x, fmaf(NL0, w04.x, c14.x));
        float ey = fmaf(NL1, w14.y, fmaf(NL0, w04.y, c14.y));
        float ez = fmaf(NL1, w14.z, fmaf(NL0, w04.z, c14.z));
        float ew = fmaf(NL1, w14.w, fmaf(NL0, w04.w, c14.w));
        float tv[4];
        tv[0] = fmaxf(fmaf(c0, va.x, fmaf(c1c, vb.x, ex)), 0.f);
        tv[1] = fmaxf(fmaf(c0, va.y, fmaf(c1c, vb.y, ey)), 0.f);
        tv[2] = fmaxf(fmaf(c0, va.z, fmaf(c1c, vb.z, ez)), 0.f);
        tv[3] = fmaxf(fmaf(c0, va.w, fmaf(c1c, vb.w, ew)), 0.f);
        #pragma unroll
        for (int k = 0; k < 4; k++) {
          const v2f* w2p = (const v2f*)&W2l[d4*4+k][0];
          v2f wA = w2p[0], wB = w2p[1], wC = w2p[2], wD = w2p[3];
          v2f tk = {tv[k], tv[k]};
          qv[0] += tk*wA; qv[1] += tk*wB; qv[2] += tk*wC; qv[3] += tk*wD;
        }
      }
      float q[8];
      #pragma unroll
      for (int h = 0; h < 4; h++) { q[2*h] = qv[h][0]; q[2*h+1] = qv[h][1]; }
      float sq[8];
      #pragma unroll
      for (int o = 0; o < 8; o++) sq[o] = mij ? q[o] : 0.f;
      #pragma unroll
      for (int off = 1; off < 32; off <<= 1) {
        #pragma unroll
        for (int o = 0; o < 8; o++) sq[o] += __shfl_xor(sq[o], off, 32);
      }
      float qd[8];
      #pragma unroll
      for (int o = 0; o < 8; o++) qd[o] = __shfl(q[o], i, 32);
      float F[8];
      if (diag) {
        #pragma unroll
        for (int o = 0; o < 8; o++) F[o] = fmaxf(sq[o]*in_, 0.f);
      } else {
        float scl = mij ? 0.5f : 1.0f;
        #pragma unroll
        for (int o = 0; o < 8; o++)
          F[o] = fmaxf((q[o] + (mij ? qd[o] : 0.f))*scl, 0.f);
      }
      #pragma unroll
      for (int off = 1; off < 32; off <<= 1) {
        #pragma unroll
        for (int o = 0; o < 8; o++) F[o] = fmaxf(F[o], __shfl_xor(F[o], off, 32));
      }
      if (j == 0) {
        #pragma unroll
        for (int o = 0; o < 8; o++) phbuf[i][myM*GO + o] = F[o];
      }
    }
    __syncthreads();

    // ---- exchange (R10 scheme: relaxed one-way data, tid0 RMW flag) ----
    {
      int sl  = (mybase + (t & 1))*SLOT;
      int psl = (pbase  + (t & 1))*SLOT;
      if (tid < 256) {
        int p = tid >> 3, o = tid & 7;
        __hip_atomic_store(ws + sl + tid, phbuf[p][myM*8 + o],
                           __ATOMIC_RELAXED, __HIP_MEMORY_SCOPE_AGENT);
      }
      __syncthreads();   // drains vmcnt in every wave -> data at coherent point
      if (tid == 0) {
        atomicExch((unsigned*)(ws + sl + 256), (unsigned)(t + 1));
        while (atomicAdd((unsigned*)(ws + psl + 256), 0u) != (unsigned)(t + 1))
          __builtin_amdgcn_s_sleep(2);
      }
      __syncthreads();
      if (tid < 256) {
        int p = tid >> 3, o = tid & 7;
        phbuf[p][(1-myM)*8 + o] =
            __hip_atomic_load(ws + psl + tid, __ATOMIC_RELAXED, __HIP_MEMORY_SCOPE_AGENT);
      }
    }
    __syncthreads();

    // P4: mlp (48 -> 64 -> 32, relu both). 32 lanes per ped (redundant in both blocks).
    {
      int p = grp32, u = lane;
      float in48[48];
      #pragma unroll
      for (int c = 0; c < 8; c++) {
        float4 v = *(const float4*)&h2buf[p][c*4];
        in48[c*4+0]=v.x; in48[c*4+1]=v.y; in48[c*4+2]=v.z; in48[c*4+3]=v.w;
      }
      #pragma unroll
      for (int c = 0; c < 4; c++) {
        float4 v = *(const float4*)&phbuf[p][c*4];
        in48[32+c*4+0]=v.x; in48[32+c*4+1]=v.y; in48[32+c*4+2]=v.z; in48[32+c*4+3]=v.w;
      }
      float m1lo = bm1l[u], m1hi = bm1l[32 + u];
      #pragma unroll
      for (int k = 0; k < 48; k++) {
        unsigned v = Wm1p[k][u];
        m1lo = fmaf(in48[k], lo16(v), m1lo);
        m1hi = fmaf(in48[k], hi16(v), m1hi);
      }
      m1lo = fmaxf(m1lo, 0.f); m1hi = fmaxf(m1hi, 0.f);
      float acc = bm2l[u];
      #pragma unroll
      for (int k = 0; k < 32; k++) {
        unsigned v = Wm2p[k][u];
        acc = fmaf(__shfl(m1lo, k, 32), lo16(v), acc);
        acc = fmaf(__shfl(m1hi, k, 32), hi16(v), acc);
      }
      hbuf[p][u] = fmaxf(acc, 0.f);
    }
    __syncthreads();
  }
}

// ==================== mono fallback: 128 blocks (R4/R6 kernel, verified) ====================
__global__ __launch_bounds__(1024, 1) void decoder_kernel_mono(
    const float* __restrict__ last_pos, const float* __restrict__ last_pos_rel,
    const float* __restrict__ hh, const float* __restrict__ ch,
    const int*  __restrict__ eg,
    const float* __restrict__ W_se, const float* __restrict__ b_se,
    const float* __restrict__ Wih, const float* __restrict__ Whh,
    const float* __restrict__ bih, const float* __restrict__ bhh,
    const float* __restrict__ W_hp, const float* __restrict__ b_hp,
    const float* __restrict__ W_pse, const float* __restrict__ b_pse,
    const float* __restrict__ W1a, const float* __restrict__ W2a,
    const float* __restrict__ W1b, const float* __restrict__ W2b,
    const float* __restrict__ W_m1, const float* __restrict__ b_m1,
    const float* __restrict__ W_m2, const float* __restrict__ b_m2,
    float* __restrict__ out)
{
  const int tid   = threadIdx.x;
  const int scn   = blockIdx.x;
  const int lane  = tid & 31;
  const int grp32 = tid >> 5;

  __shared__ __align__(16) float uni[4864];
  __shared__ __align__(16) unsigned W1p[2][16][GH];
  __shared__ __align__(16) float W2l[2][GH][GO];
  __shared__ __align__(16) float Wp1[2][2][GH];
  __shared__ __align__(16) float c1l[2][GH];
  __shared__ __align__(16) float hbuf[NP][HD];
  __shared__ __align__(16) float h2buf[NP][36];
  __shared__ __align__(16) float GS[2][5][GH];
  __shared__ __align__(16) float phbuf[NP][16];
  __shared__ __align__(16) unsigned Wm1p[48][32];
  __shared__ __align__(16) unsigned Wm2p[32][32];
  __shared__ float lpbuf[NP][2], rpbuf[NP][2], Whp[HD][2];
  __shared__ float bm1l[MD], bm2l[HD], bhp2[2];
  __shared__ unsigned bm[2][NP];
  __shared__ float invn[2][NP];
  __shared__ int gl[NP];

  const int myrow = tid & 127;
  const int pq4   = tid >> 7;
  float wrow[HD];
  #pragma unroll
  for (int c = 0; c < HD/4; c++) {
    float4 w = *(const float4*)(Whh + myrow*HD + c*4);
    wrow[c*4+0]=w.x; wrow[c*4+1]=w.y; wrow[c*4+2]=w.z; wrow[c*4+3]=w.w;
  }
  float wf0 = 0.f, wf1 = 0.f, bfr = bih[myrow] + bhh[myrow];
  #pragma unroll
  for (int e = 0; e < ED; e++) {
    float wv = Wih[myrow*ED + e];
    wf0 = fmaf(W_se[e],    wv, wf0);
    wf1 = fmaf(W_se[ED+e], wv, wf1);
    bfr = fmaf(b_se[e],    wv, bfr);
  }
  float creg = ch[(scn*NP + grp32)*HD + lane];
  hbuf[grp32][lane] = hh[(scn*NP + grp32)*HD + lane];

  if (tid < NP) {
    int gi = eg[scn*NP + tid];
    gl[tid] = gi;
    unsigned sm = 0;
    for (int j = 0; j < NP; j++) {
      int gj = eg[scn*NP + j];
      bool sj = (j == tid) || (gi == gj && gi != 0);
      sm |= ((unsigned)sj) << j;
    }
    unsigned dm = (~sm) | (1u << tid);
    bm[0][tid] = sm; bm[1][tid] = dm;
    invn[0][tid] = 1.0f/(float)__popc(sm);
    invn[1][tid] = 1.0f/(float)__popc(dm);
  }
  if (tid < 64) {
    int p = tid >> 1, k = tid & 1;
    lpbuf[p][k] = last_pos[(scn*NP+p)*2+k];
    rpbuf[p][k] = last_pos_rel[(scn*NP+p)*2+k];
    Whp[p][k]   = W_hp[tid];
    bm1l[tid]   = b_m1[tid];
  }
  if (tid < 32) bm2l[tid] = b_m2[tid];
  if (tid < 2)  bhp2[tid] = b_hp[tid];
  if (tid < 2*GH) {
    int m = tid / GH, d = tid % GH;
    const float* W1 = m ? W1b : W1a;
    float s0 = 0.f, s1 = 0.f, sc1 = 0.f;
    for (int e = 0; e < ED; e++) {
      float w = W1[e*GH + d];
      s0 += W_pse[e]*w; s1 += W_pse[ED+e]*w; sc1 += b_pse[e]*w;
    }
    Wp1[m][0][d] = s0; Wp1[m][1][d] = s1; c1l[m][d] = sc1;
  }
  {
    int u = tid;
    if (u < 2*GH*GO) {
      int m = u/(GH*GO), rest = u%(GH*GO);
      W2l[m][rest/GO][rest%GO] = (m ? W2b : W2a)[rest];
    }
    if (tid < 128) {
      int u2 = tid + 1024;
      int m = u2/(GH*GO), rest = u2%(GH*GO);
      W2l[m][rest/GO][rest%GO] = (m ? W2b : W2a)[rest];
    }
  }
  #pragma unroll
  for (int r = 0; r < 3; r++) {
    int u = tid + 1024*r;
    if (u < 2304) {
      int m = u/1152, rest = u%1152, k2 = rest/GH, d = rest%GH;
      const float* W1 = m ? W1b : W1a;
      W1p[m][k2][d] = rne16(W1[(ED+2*k2)*GH + d]) | (rne16(W1[(ED+2*k2+1)*GH + d]) << 16);
    }
  }
  #pragma unroll
  for (int r = 0; r < 2; r++) {
    int u = tid + 1024*r;
    if (u < 1536) {
      int k = u >> 5, uu = u & 31;
      Wm1p[k][uu] = rne16(W_m1[k*MD + uu]) | (rne16(W_m1[k*MD + 32 + uu]) << 16);
    }
  }
  {
    int k = tid >> 5, uu = tid & 31;
    Wm2p[k][uu] = rne16(W_m2[k*HD + uu]) | (rne16(W_m2[(k+32)*HD + uu]) << 16);
  }
  __syncthreads();

  for (int t = 0; t < TT; t++) {
    {
      float rG[4];
      #pragma unroll
      for (int pp2 = 0; pp2 < 4; pp2++) {
        int p = pq4*4 + pp2;
        float acc = fmaf(rpbuf[p][0], wf0, fmaf(rpbuf[p][1], wf1, bfr));
        #pragma unroll
        for (int c = 0; c < 8; c++) {
          float4 h4 = *(const float4*)&hbuf[p][c*4];
          acc = fmaf(h4.x, wrow[c*4+0], acc);
          acc = fmaf(h4.y, wrow[c*4+1], acc);
          acc = fmaf(h4.z, wrow[c*4+2], acc);
          acc = fmaf(h4.w, wrow[c*4+3], acc);
        }
        rG[pp2] = acc;
      }
      #pragma unroll
      for (int pp2 = 0; pp2 < 4; pp2++) uni[(pq4*4+pp2)*128 + myrow] = rG[pp2];
    }
    __syncthreads();
    {
      int p = grp32, n = lane;
      float gi_ = uni[p*128 + n];
      float gf_ = uni[p*128 + 32 + n];
      float gg_ = uni[p*128 + 64 + n];
      float go_ = uni[p*128 + 96 + n];
      float c2 = sigm(gf_)*creg + sigm(gi_)*tanhfast(gg_);
      creg = c2;
      float h2 = sigm(go_)*tanhfast(c2);
      h2buf[p][n] = h2;
      float r0 = h2 * Whp[n][0];
      float r1 = h2 * Whp[n][1];
      #pragma unroll
      for (int off = 1; off < 32; off <<= 1) {
        r0 += __shfl_xor(r0, off, 32);
        r1 += __shfl_xor(r1, off, 32);
      }
      r0 += bhp2[0]; r1 += bhp2[1];
      if (n == 0) {
        out[t*NB*2 + (scn*NP+p)*2 + 0] = r0;
        out[t*NB*2 + (scn*NP+p)*2 + 1] = r1;
        rpbuf[p][0] = r0;  rpbuf[p][1] = r1;
        lpbuf[p][0] += r0; lpbuf[p][1] += r1;
      }
    }
    __syncthreads();
    {
      const int j = lane;
      float lpj0 = lpbuf[j][0], lpj1 = lpbuf[j][1];
      float h2row[HD];
      #pragma unroll
      for (int c = 0; c < 8; c++) {
        float4 v = *(const float4*)&h2buf[j][c*4];
        h2row[c*4+0]=v.x; h2row[c*4+1]=v.y; h2row[c*4+2]=v.z; h2row[c*4+3]=v.w;
      }
      #pragma unroll
      for (int r = 0; r < 5; r++) {
        int rest = grp32 + 32*r;
        if (rest < 144) {
          int m = rest >= 72 ? 1 : 0;
          int d = rest - 72*m;
          float pp_ = fmaf(lpj0, Wp1[m][0][d], lpj1*Wp1[m][1][d]);
          float av = pp_;
          #pragma unroll
          for (int k2 = 0; k2 < 16; k2++) {
            unsigned v = W1p[m][k2][d];
            av = fmaf(h2row[2*k2], lo16(v), av);
            av = fmaf(h2row[2*k2+1], hi16(v), av);
          }
          uni[m*2432 + j*76 + d] = av;
          int gj = gl[j];
          float tot = av;
          float s1 = (gj==1)?av:0.f, s2=(gj==2)?av:0.f, s3=(gj==3)?av:0.f, s4=(gj==4)?av:0.f;
          #pragma unroll
          for (int off = 1; off < 32; off <<= 1) {
            tot += __shfl_xor(tot, off, 32);
            s1 += __shfl_xor(s1, off, 32);
            s2 += __shfl_xor(s2, off, 32);
            s3 += __shfl_xor(s3, off, 32);
            s4 += __shfl_xor(s4, off, 32);
          }
          if (j < 5) {
            float v2;
            if (m == 0) v2 = (j==0)?tot:((j==1)?s1:((j==2)?s2:((j==3)?s3:s4)));
            else        v2 = (j==0)?tot:((j==1)?tot-s1:((j==2)?tot-s2:((j==3)?tot-s3:tot-s4)));
            GS[m][j][d] = v2;
          }
        }
      }
    }
    __syncthreads();
    {
      const int j   = lane;
      const int m   = tid >> 9;
      const int sub = (tid >> 5) & 15;
      const float* am = uni + m*2432;
      int   I2[2] = {sub, sub + 16};
      const float *P0[2], *P1[2];
      float C0[2], C1[2], NL0[2], NL1[2];
      bool  MIJ[2], DIAG[2];
      v2f qv[2][4];
      #pragma unroll
      for (int r = 0; r < 2; r++) {
        int i = I2[r];
        unsigned bmv = bm[m][i];
        bool mij = (bmv >> j) & 1u;
        bool diag = (j == i);
        int gi = gl[i];
        float in_ = invn[m][i];
        const float *p0, *p1; float c0, c1c;
        if (diag) {
          if (m == 0) { p0 = gi ? &GS[0][gi][0] : (am + i*76); c0 = in_; p1 = am + i*76; c1c = 0.f; }
          else        { p0 = &GS[1][gi][0];                    c0 = in_; p1 = am + i*76; c1c = gi ? in_ : 0.f; }
        } else if (mij) { p0 = am + j*76; c0 = 0.5f; p1 = am + i*76; c1c = 0.5f; }
        else            { p0 = am + j*76; c0 = 1.0f; p1 = am + j*76; c1c = 0.f; }
        P0[r]=p0; P1[r]=p1; C0[r]=c0; C1[r]=c1c; MIJ[r]=mij; DIAG[r]=diag;
        NL0[r] = -lpbuf[i][0]; NL1[r] = -lpbuf[i][1];
        #pragma unroll
        for (int h = 0; h < 4; h++) qv[r][h] = (v2f){0.f, 0.f};
      }
      for (int d4 = 0; d4 < GH/4; d4++) {
        float4 c14 = *(const float4*)&c1l[m][d4*4];
        float4 w04 = *(const float4*)&Wp1[m][0][d4*4];
        float4 w14 = *(const float4*)&Wp1[m][1][d4*4];
        float4 vaS = *(const float4*)(am + j*76 + d4*4);
        float4 va0 = vaS, va1 = vaS;
        if (DIAG[0]) va0 = *(const float4*)(P0[0] + d4*4);
        if (DIAG[1]) va1 = *(const float4*)(P0[1] + d4*4);
        float4 vb0 = *(const float4*)(P1[0] + d4*4);
        float4 vb1 = *(const float4*)(P1[1] + d4*4);
        float e0x = fmaf(NL1[0], w14.x, fmaf(NL0[0], w04.x, c14.x));
        float e0y = fmaf(NL1[0], w14.y, fmaf(NL0[0], w04.y, c14.y));
        float e0z = fmaf(NL1[0], w14.z, fmaf(NL0[0], w04.z, c14.z));
        float e0w = fmaf(NL1[0], w14.w, fmaf(NL0[0], w04.w, c14.w));
        float e1x = fmaf(NL1[1], w14.x, fmaf(NL0[1], w04.x, c14.x));
        float e1y = fmaf(NL1[1], w14.y, fmaf(NL0[1], w04.y, c14.y));
        float e1z = fmaf(NL1[1], w14.z, fmaf(NL0[1], w04.z, c14.z));
        float e1w = fmaf(NL1[1], w14.w, fmaf(NL0[1], w04.w, c14.w));
        float tv0[4], tv1[4];
        tv0[0] = fmaxf(fmaf(C0[0], va0.x, fmaf(C1[0], vb0.x, e0x)), 0.f);
        tv0[1] = fmaxf(fmaf(C0[0], va0.y, fmaf(C1[0], vb0.y, e0y)), 0.f);
        tv0[2] = fmaxf(fmaf(C0[0], va0.z, fmaf(C1[0], vb0.z, e0z)), 0.f);
        tv0[3] = fmaxf(fmaf(C0[0], va0.w, fmaf(C1[0], vb0.w, e0w)), 0.f);
        tv1[0] = fmaxf(fmaf(C0[1], va1.x, fmaf(C1[1], vb1.x, e1x)), 0.f);
        tv1[1] = fmaxf(fmaf(C0[1], va1.y, fmaf(C1[1], vb1.y, e1y)), 0.f);
        tv1[2] = fmaxf(fmaf(C0[1], va1.z, fmaf(C1[1], vb1.z, e1z)), 0.f);
        tv1[3] = fmaxf(fmaf(C0[1], va1.w, fmaf(C1[1], vb1.w, e1w)), 0.f);
        #pragma unroll
        for (int k = 0; k < 4; k++) {
          const v2f* w2p = (const v2f*)&W2l[m][d4*4+k][0];
          v2f wA = w2p[0], wB = w2p[1], wC = w2p[2], wD = w2p[3];
          v2f t0 = {tv0[k], tv0[k]};
          qv[0][0] += t0*wA; qv[0][1] += t0*wB; qv[0][2] += t0*wC; qv[0][3] += t0*wD;
          v2f t1 = {tv1[k], tv1[k]};
          qv[1][0] += t1*wA; qv[1][1] += t1*wB; qv[1][2] += t1*wC; qv[1][3] += t1*wD;
        }
      }
      #pragma unroll
      for (int r = 0; r < 2; r++) {
        float q[8];
        #pragma unroll
        for (int h = 0; h < 4; h++) { q[2*h] = qv[r][h][0]; q[2*h+1] = qv[r][h][1]; }
        float sq[8];
        #pragma unroll
        for (int o = 0; o < 8; o++) sq[o] = MIJ[r] ? q[o] : 0.f;
        #pragma unroll
        for (int off = 1; off < 32; off <<= 1) {
          #pragma unroll
          for (int o = 0; o < 8; o++) sq[o] += __shfl_xor(sq[o], off, 32);
        }
        float qd[8];
        #pragma unroll
        for (int o = 0; o < 8; o++) qd[o] = __shfl(q[o], I2[r], 32);
        float in_ = invn[m][I2[r]];
        float F[8];
        if (DIAG[r]) {
          #pragma unroll
          for (int o = 0; o < 8; o++) F[o] = fmaxf(sq[o]*in_, 0.f);
        } else {
          float scl = MIJ[r] ? 0.5f : 1.0f;
          #pragma unroll
          for (int o = 0; o < 8; o++)
            F[o] = fmaxf((q[o] + (MIJ[r] ? qd[o] : 0.f))*scl, 0.f);
        }
        #pragma unroll
        for (int off = 1; off < 32; off <<= 1) {
          #pragma unroll
          for (int o = 0; o < 8; o++) F[o] = fmaxf(F[o], __shfl_xor(F[o], off, 32));
        }
        if (j == 0) {
          #pragma unroll
          for (int o = 0; o < 8; o++) phbuf[I2[r]][m*GO + o] = F[o];
        }
      }
    }
    __syncthreads();
    {
      int p = grp32, u = lane;
      float in48[48];
      #pragma unroll
      for (int c = 0; c < 8; c++) {
        float4 v = *(const float4*)&h2buf[p][c*4];
        in48[c*4+0]=v.x; in48[c*4+1]=v.y; in48[c*4+2]=v.z; in48[c*4+3]=v.w;
      }
      #pragma unroll
      for (int c = 0; c < 4; c++) {
        float4 v = *(const float4*)&phbuf[p][c*4];
        in48[32+c*4+0]=v.x; in48[32+c*4+1]=v.y; in48[32+c*4+2]=v.z; in48[32+c*4+3]=v.w;
      }
      float m1lo = bm1l[u], m1hi = bm1l[32 + u];
      #pragma unroll
      for (int k = 0; k < 48; k++) {
        unsigned v = Wm1p[k][u];
        m1lo = fmaf(in48[k], lo16(v), m1lo);
        m1hi = fmaf(in48[k], hi16(v), m1hi);
      }
      m1lo = fmaxf(m1lo, 0.f); m1hi = fmaxf(m1hi, 0.f);
      float acc = bm2l[u];
      #pragma unroll
      for (int k = 0; k < 32; k++) {
        unsigned v = Wm2p[k][u];
        acc = fmaf(__shfl(m1lo, k, 32), lo16(v), acc);
        acc = fmaf(__shfl(m1hi, k, 32), hi16(v), acc);
      }
      hbuf[p][u] = fmaxf(acc, 0.f);
    }
    __syncthreads();
  }
}

extern "C" void kernel_launch(void* const* d_in, const int* in_sizes, int n_in,
                              void* d_out, int out_size, void* d_ws, size_t ws_size,
                              hipStream_t stream) {
  (void)in_sizes; (void)n_in; (void)out_size;
  const float* last_pos     = (const float*)d_in[0];
  const float* last_pos_rel = (const float*)d_in[1];
  const float* hh           = (const float*)d_in[2];
  const float* ch           = (const float*)d_in[3];
  const int*  eg            = (const int*) d_in[5];
  const float* W_se  = (const float*)d_in[6];
  const float* b_se  = (const float*)d_in[7];
  const float* Wih   = (const float*)d_in[8];
  const float* Whh   = (const float*)d_in[9];
  const float* bih   = (const float*)d_in[10];
  const float* bhh   = (const float*)d_in[11];
  const float* W_hp  = (const float*)d_in[12];
  const float* b_hp  = (const float*)d_in[13];
  const float* W_pse = (const float*)d_in[14];
  const float* b_pse = (const float*)d_in[15];
  const float* W1a   = (const float*)d_in[16];
  const float* W2a   = (const float*)d_in[17];
  const float* W1b   = (const float*)d_in[18];
  const float* W2b   = (const float*)d_in[19];
  const float* W_m1  = (const float*)d_in[20];
  const float* b_m1  = (const float*)d_in[21];
  const float* W_m2  = (const float*)d_in[22];
  const float* b_m2  = (const float*)d_in[23];
  float* out = (float*)d_out;

  if (ws_size >= (size_t)WS_NEED) {
    decoder_kernel_split<<<2*NS, 1024, 0, stream>>>(
        last_pos, last_pos_rel, hh, ch, eg,
        W_se, b_se, Wih, Whh, bih, bhh, W_hp, b_hp, W_pse, b_pse,
        W1a, W2a, W1b, W2b, W_m1, b_m1, W_m2, b_m2, out, (float*)d_ws);
  } else {
    decoder_kernel_mono<<<NS, 1024, 0, stream>>>(
        last_pos, last_pos_rel, hh, ch, eg,
        W_se, b_se, Wih, Whh, bih, bhh, W_hp, b_hp, W_pse, b_pse,
        W1a, W2a, W1b, W2b, W_m1, b_m1, W_m2, b_m2, out);
  }
}